// Round 13
// baseline (408.512 us; speedup 1.0000x reference)
//
#include <hip/hip_runtime.h>

#define D 128
#define GNUM 64
#define LNUM 4
#define BN_EPS 1e-5f
#define EPB 16384          // edges per hist/scatter block
#define SH_MAX 12544       // max NBIN*B the one-block scan supports

typedef short bf16x8 __attribute__((ext_vector_type(8)));       // 8 bf16 = 4 VGPR
typedef float f32x4 __attribute__((ext_vector_type(4)));
typedef unsigned short u16x8 __attribute__((ext_vector_type(8)));
typedef unsigned short u16x4 __attribute__((ext_vector_type(4)));

__device__ __forceinline__ float bf2f(unsigned short u) {
  union { unsigned int i; float f; } v; v.i = ((unsigned int)u) << 16; return v.f;
}
__device__ __forceinline__ unsigned short f2bf(float f) {
  union { float f; unsigned int i; } v; v.f = f;
  unsigned int b = v.i;
  return (unsigned short)((b + 0x7FFFu + ((b >> 16) & 1u)) >> 16);
}

// ---------------- CSR build: atomic-free binned counting sort ----------------
__global__ __launch_bounds__(256) void k_hist(const int* __restrict__ ei, int E,
                                              int B, int nbin, int* __restrict__ hist) {
  __shared__ int lh[256];
  int b = blockIdx.x, tx = threadIdx.x;
  lh[tx] = 0;
  __syncthreads();
  int s = b * EPB, e = min(s + EPB, E);
  for (int j = s + tx; j < e; j += 256) atomicAdd(&lh[ei[(size_t)E + j] >> 8], 1);
  __syncthreads();
  if (tx < nbin) hist[tx * B + b] = lh[tx];
}

// one-block scan of hist; also graph bounds (binary search) + ctr zero
__global__ __launch_bounds__(1024) void k_hscan(const int* __restrict__ hist, int M,
                                                int* __restrict__ off,
                                                int* __restrict__ rowptr, int N, int E,
                                                const int* __restrict__ batch,
                                                int* __restrict__ bound,
                                                int* __restrict__ ctr) {
  __shared__ int sh[SH_MAX];
  __shared__ int sh2[1024];
  int tx = threadIdx.x;
  int chunk = (M + 1023) / 1024;
  for (int i = 0; i < chunk; ++i) {
    int idx = tx * chunk + i;
    sh[idx] = (idx < M) ? hist[idx] : 0;
  }
  __syncthreads();
  int s = 0;
  for (int i = 0; i < chunk; ++i) s += sh[tx * chunk + i];
  sh2[tx] = s;
  __syncthreads();
  for (int o = 1; o < 1024; o <<= 1) {
    int u = (tx >= o) ? sh2[tx - o] : 0;
    __syncthreads();
    sh2[tx] += u;
    __syncthreads();
  }
  int run = (tx == 0) ? 0 : sh2[tx - 1];
  for (int i = 0; i < chunk; ++i) {
    int idx = tx * chunk + i;
    if (idx < M) { int v = sh[idx]; off[idx] = run; run += v; }
  }
  if (tx == 0) { rowptr[N] = E; ctr[0] = 0; }
  if (tx <= GNUM) {            // graph boundaries on sorted batch
    int g = tx, lo = 0, hi = N;
    while (lo < hi) { int mid = (lo + hi) >> 1; if (batch[mid] < g) lo = mid + 1; else hi = mid; }
    bound[g] = lo;
  }
}

__global__ __launch_bounds__(256) void k_scatter(const int* __restrict__ ei, int E,
                                                 int B, int nbin,
                                                 const int* __restrict__ off,
                                                 int2* __restrict__ sorted) {
  __shared__ int cur[256];
  int b = blockIdx.x, tx = threadIdx.x;
  if (tx < nbin) cur[tx] = off[tx * B + b];
  __syncthreads();
  int s = b * EPB, e = min(s + EPB, E);
  for (int j = s + tx; j < e; j += 256) {
    int d = ei[(size_t)E + j];
    int sc = ei[j];
    int p = atomicAdd(&cur[d >> 8], 1);
    sorted[p] = make_int2(d, sc);
  }
}

__global__ __launch_bounds__(256) void k_build(const int2* __restrict__ sorted,
                                               const int* __restrict__ off,
                                               int B, int nbin, int E, int N,
                                               int* __restrict__ rowptr,
                                               int* __restrict__ col) {
  __shared__ int cnt[256], excl[256], cur[256];
  int beta = blockIdx.x, tx = threadIdx.x;
  int s = off[beta * B];
  int e = (beta + 1 < nbin) ? off[(beta + 1) * B] : E;
  cnt[tx] = 0;
  __syncthreads();
  for (int j = s + tx; j < e; j += 256) atomicAdd(&cnt[sorted[j].x & 255], 1);
  __syncthreads();
  int v = cnt[tx];
  excl[tx] = v;
  __syncthreads();
  for (int o = 1; o < 256; o <<= 1) {
    int u = (tx >= o) ? excl[tx - o] : 0;
    __syncthreads();
    excl[tx] += u;
    __syncthreads();
  }
  int ex = excl[tx] - v;
  int n = beta * 256 + tx;
  if (n < N) rowptr[n] = s + ex;
  cur[tx] = s + ex;
  __syncthreads();
  for (int j = s + tx; j < e; j += 256) {
    int2 p = sorted[j];
    int q = atomicAdd(&cur[p.x & 255], 1);
    col[q] = p.y;
  }
}

// per-64-tile degree rank: perm[r0+rank] = local row (pads rank first)
__global__ __launch_bounds__(64) void k_perm(const int* __restrict__ rowptr, int N,
                                             int* __restrict__ perm) {
  __shared__ int degs[64];
  int r0 = blockIdx.x * 64;
  int i = threadIdx.x;
  int n = r0 + i;
  int d = (n < N) ? (rowptr[n + 1] - rowptr[n]) : -1;
  degs[i] = d;
  __syncthreads();
  int rank = 0;
#pragma unroll
  for (int j = 0; j < 64; ++j) {
    int dj = degs[j];
    if (dj < d || (dj == d && j < i)) ++rank;
  }
  perm[r0 + rank] = i;
}

// ---------------- prep ----------------
__global__ void k_prep_x(const float* __restrict__ x, unsigned short* __restrict__ hx, int total4) {
  int i = blockIdx.x * 256 + threadIdx.x;
  if (i < total4) {
    f32x4 v = ((const f32x4*)x)[i];
    u16x4 o; o[0] = f2bf(v[0]); o[1] = f2bf(v[1]); o[2] = f2bf(v[2]); o[3] = f2bf(v[3]);
    ((u16x4*)hx)[i] = o;
  }
}

__global__ __launch_bounds__(256) void k_prep_w(const float* __restrict__ W1,
                                                const float* __restrict__ W2,
                                                unsigned short* __restrict__ wt) {
  int l = blockIdx.x;
  const float* W = (l < LNUM) ? (W1 + (size_t)l * D * D) : (W2 + (size_t)(l - LNUM) * D * D);
  unsigned short* o = wt + (size_t)l * D * D;
#pragma unroll
  for (int i = 0; i < 64; ++i) {
    int idx = threadIdx.x + 256 * i;       // idx = k*128 + n
    int k = idx >> 7, n = idx & 127;
    o[n * D + k] = f2bf(W[idx]);
  }
}

// ---------------- fused layer-1: reg-direct gather, degree-sorted slots,
// masked 4-wide tail (every round issues 16 loads) ----------------
__global__ __launch_bounds__(256, 3) void k_layer1(const unsigned short* __restrict__ hin,
                                                const int* __restrict__ rowptr,
                                                const int* __restrict__ col,
                                                const int* __restrict__ perm,
                                                const unsigned short* __restrict__ wt,
                                                const float* __restrict__ bias,
                                                unsigned short* __restrict__ t,
                                                float* __restrict__ partials, int N) {
  __shared__ union { unsigned short wl[D * D]; float out[64 * D]; } uB;  // 32KB
  __shared__ float red[2 * 8 * D];                                      // 8KB
  int tx = threadIdx.x;
  int r0 = blockIdx.x * 64;
  const u16x8* wg = (const u16x8*)wt;
#pragma unroll
  for (int i = 0; i < 8; ++i) {
    int cid = tx + 256 * i;
    int row = cid >> 4, c16 = cid & 15;
    u16x8 v = wg[cid];
    *(u16x8*)((char*)uB.wl + row * 256 + ((c16 * 16) ^ ((row & 7) << 4))) = v;
  }
  int l = tx & 63, w = tx >> 6;
  int lm = l & 15, lg = l >> 4;
  int lr = perm[r0 + 16 * w + lm];
  int pr0 = perm[r0 + 16 * w + 4 * lg + 0];
  int pr1 = perm[r0 + 16 * w + 4 * lg + 1];
  int pr2 = perm[r0 + 16 * w + 4 * lg + 2];
  int pr3 = perm[r0 + 16 * w + 4 * lg + 3];
  int n = r0 + lr;
  const u16x8* h8 = (const u16x8*)hin;
  f32x4 sA[4] = {{0.f,0.f,0.f,0.f},{0.f,0.f,0.f,0.f},{0.f,0.f,0.f,0.f},{0.f,0.f,0.f,0.f}};
  f32x4 sB[4] = {{0.f,0.f,0.f,0.f},{0.f,0.f,0.f,0.f},{0.f,0.f,0.f,0.f},{0.f,0.f,0.f,0.f}};
  int e0 = 0, e1 = 0;
  if (n < N) { e0 = rowptr[n]; e1 = rowptr[n + 1]; }
  int jb = e1 - 1;
  for (int j = e0; j < e1; j += 4) {          // always 16 x 16B loads in flight
    int i1 = (j + 1 <= jb) ? j + 1 : jb;
    int i2 = (j + 2 <= jb) ? j + 2 : jb;
    int i3 = (j + 3 <= jb) ? j + 3 : jb;
    size_t a0i = (size_t)col[j]  * 16 + lg;
    size_t a1i = (size_t)col[i1] * 16 + lg;
    size_t a2i = (size_t)col[i2] * 16 + lg;
    size_t a3i = (size_t)col[i3] * 16 + lg;
    u16x8 u00 = h8[a0i], u01 = h8[a0i + 4], u02 = h8[a0i + 8], u03 = h8[a0i + 12];
    u16x8 u10 = h8[a1i], u11 = h8[a1i + 4], u12 = h8[a1i + 8], u13 = h8[a1i + 12];
    u16x8 u20 = h8[a2i], u21 = h8[a2i + 4], u22 = h8[a2i + 8], u23 = h8[a2i + 12];
    u16x8 u30 = h8[a3i], u31 = h8[a3i + 4], u32 = h8[a3i + 8], u33 = h8[a3i + 12];
    float m1 = (j + 1 < e1) ? 1.f : 0.f;
    float m2 = (j + 2 < e1) ? 1.f : 0.f;
    float m3 = (j + 3 < e1) ? 1.f : 0.f;
#pragma unroll
    for (int k = 0; k < 4; ++k) {
      sA[0][k] += bf2f(u00[k]);
      sA[0][k] = fmaf(m1, bf2f(u10[k]), sA[0][k]);
      sA[0][k] = fmaf(m2, bf2f(u20[k]), sA[0][k]);
      sA[0][k] = fmaf(m3, bf2f(u30[k]), sA[0][k]);
      sB[0][k] += bf2f(u00[4+k]);
      sB[0][k] = fmaf(m1, bf2f(u10[4+k]), sB[0][k]);
      sB[0][k] = fmaf(m2, bf2f(u20[4+k]), sB[0][k]);
      sB[0][k] = fmaf(m3, bf2f(u30[4+k]), sB[0][k]);
      sA[1][k] += bf2f(u01[k]);
      sA[1][k] = fmaf(m1, bf2f(u11[k]), sA[1][k]);
      sA[1][k] = fmaf(m2, bf2f(u21[k]), sA[1][k]);
      sA[1][k] = fmaf(m3, bf2f(u31[k]), sA[1][k]);
      sB[1][k] += bf2f(u01[4+k]);
      sB[1][k] = fmaf(m1, bf2f(u11[4+k]), sB[1][k]);
      sB[1][k] = fmaf(m2, bf2f(u21[4+k]), sB[1][k]);
      sB[1][k] = fmaf(m3, bf2f(u31[4+k]), sB[1][k]);
      sA[2][k] += bf2f(u02[k]);
      sA[2][k] = fmaf(m1, bf2f(u12[k]), sA[2][k]);
      sA[2][k] = fmaf(m2, bf2f(u22[k]), sA[2][k]);
      sA[2][k] = fmaf(m3, bf2f(u32[k]), sA[2][k]);
      sB[2][k] += bf2f(u02[4+k]);
      sB[2][k] = fmaf(m1, bf2f(u12[4+k]), sB[2][k]);
      sB[2][k] = fmaf(m2, bf2f(u22[4+k]), sB[2][k]);
      sB[2][k] = fmaf(m3, bf2f(u32[4+k]), sB[2][k]);
      sA[3][k] += bf2f(u03[k]);
      sA[3][k] = fmaf(m1, bf2f(u13[k]), sA[3][k]);
      sA[3][k] = fmaf(m2, bf2f(u23[k]), sA[3][k]);
      sA[3][k] = fmaf(m3, bf2f(u33[k]), sA[3][k]);
      sB[3][k] += bf2f(u03[4+k]);
      sB[3][k] = fmaf(m1, bf2f(u13[4+k]), sB[3][k]);
      sB[3][k] = fmaf(m2, bf2f(u23[4+k]), sB[3][k]);
      sB[3][k] = fmaf(m3, bf2f(u33[4+k]), sB[3][k]);
    }
  }
  bf16x8 af[4];
  if (n < N) {
    float inv = (e1 > e0) ? 1.f / (float)(e1 - e0) : 0.f;
#pragma unroll
    for (int kt = 0; kt < 4; ++kt) {
      u16x8 hv = h8[(size_t)n * 16 + kt * 4 + lg];
      u16x8 o;
#pragma unroll
      for (int k = 0; k < 4; ++k) {
        o[k] = f2bf(bf2f(hv[k]) + sA[kt][k] * inv);
        o[4 + k] = f2bf(bf2f(hv[4 + k]) + sB[kt][k] * inv);
      }
      af[kt] = *(bf16x8*)&o;
    }
  } else {
#pragma unroll
    for (int kt = 0; kt < 4; ++kt) af[kt] = (bf16x8){0,0,0,0,0,0,0,0};
  }
  __syncthreads();   // W staged
  f32x4 acc[8];
#pragma unroll
  for (int cc = 0; cc < 8; ++cc) { float bv = bias[cc * 16 + lm]; acc[cc] = (f32x4){bv, bv, bv, bv}; }
#pragma unroll
  for (int kt = 0; kt < 4; ++kt) {
    int koff = kt * 64 + lg * 16;
#pragma unroll
    for (int cc = 0; cc < 8; ++cc) {
      int nn = cc * 16 + lm;
      bf16x8 bfr = *(const bf16x8*)((const char*)uB.wl + nn * 256 + (koff ^ ((nn & 7) << 4)));
      acc[cc] = __builtin_amdgcn_mfma_f32_16x16x32_bf16(af[kt], bfr, acc[cc], 0, 0, 0);
    }
  }
  __syncthreads();  // wl free -> out
#pragma unroll
  for (int cc = 0; cc < 8; ++cc) {          // write via perm: natural row order
    uB.out[pr0 * D + cc * 16 + lm] = acc[cc][0];
    uB.out[pr1 * D + cc * 16 + lm] = acc[cc][1];
    uB.out[pr2 * D + cc * 16 + lm] = acc[cc][2];
    uB.out[pr3 * D + cc * 16 + lm] = acc[cc][3];
  }
  __syncthreads();
  int tc = tx & 31, tr = tx >> 5;
  f32x4 s = {0.f, 0.f, 0.f, 0.f}, q = {0.f, 0.f, 0.f, 0.f};
#pragma unroll
  for (int i = 0; i < 8; ++i) {
    int rr = i * 8 + tr;
    f32x4 v = *(f32x4*)&uB.out[rr * D + tc * 4];
    u16x4 o; o[0] = f2bf(v[0]); o[1] = f2bf(v[1]); o[2] = f2bf(v[2]); o[3] = f2bf(v[3]);
    *(u16x4*)(t + (size_t)(r0 + rr) * D + tc * 4) = o;
    if (r0 + rr < N) { s += v; q += v * v; }
  }
  *(f32x4*)&red[tr * D + tc * 4] = s;
  *(f32x4*)&red[8 * D + tr * D + tc * 4] = q;
  __syncthreads();
  int colx = tx & 127, which = tx >> 7;
  float S = 0.f;
#pragma unroll
  for (int jj = 0; jj < 8; ++jj) S += red[which * 8 * D + jj * D + colx];
  partials[(size_t)blockIdx.x * 256 + tx] = S;
}

// fused reduce: 64 blocks; last block (atomic counter) finalizes stats.
// Cross-XCD intra-kernel reads via agent-scope atomic loads (L2 non-coherence).
__global__ __launch_bounds__(256) void k_red1fin(const float* __restrict__ partials, int NB,
                                                 float* __restrict__ partial2,
                                                 const float* __restrict__ gamma,
                                                 const float* __restrict__ beta,
                                                 float* __restrict__ stats, int N,
                                                 int* __restrict__ ctr) {
  __shared__ int isLast;
  __shared__ float sh[256];
  int tx = threadIdx.x;
  float S = 0.f;
  for (int b = blockIdx.x; b < NB; b += 64) S += partials[(size_t)b * 256 + tx];
  partial2[(size_t)blockIdx.x * 256 + tx] = S;
  __threadfence();
  if (tx == 0) isLast = (atomicAdd(ctr, 1) == 63) ? 1 : 0;
  __syncthreads();
  if (isLast) {
    __threadfence();  // acquire before reading other blocks' partial2
    float T = 0.f;
#pragma unroll 8
    for (int b = 0; b < 64; ++b)
      T += __hip_atomic_load(&partial2[(size_t)b * 256 + tx], __ATOMIC_RELAXED,
                             __HIP_MEMORY_SCOPE_AGENT);
    sh[tx] = T;
    __syncthreads();
    if (tx < D) {
      float mu = sh[tx] / (float)N;
      float var = sh[D + tx] / (float)N - mu * mu;
      float rstd = rsqrtf(fmaxf(var, 0.f) + BN_EPS);
      float A = gamma[tx] * rstd;
      stats[tx] = A;
      stats[D + tx] = beta[tx] - mu * A;
    }
    if (tx == 0) ctr[0] = 0;   // ready for next layer / next call
  }
}

// ---------------- GEMM2 core v2: register-direct A ----------------
__device__ __forceinline__ void gemm2_core(const unsigned short* t,
                                           const unsigned short* wt,
                                           const float* bias, const float* stats,
                                           unsigned short* wl, float* outbuf, int r0) {
  int tx = threadIdx.x;
  const u16x8* wg = (const u16x8*)wt;
#pragma unroll
  for (int i = 0; i < 8; ++i) {
    int cid = tx + 256 * i;
    int row = cid >> 4, c16 = cid & 15;
    u16x8 v = wg[cid];
    *(u16x8*)((char*)wl + row * 256 + ((c16 * 16) ^ ((row & 7) << 4))) = v;
  }
  int l = tx & 63, w = tx >> 6;
  int lm = l & 15, lg = l >> 4;
  int row = 16 * w + lm;
  const u16x8* tg8 = (const u16x8*)(t + (size_t)(r0 + row) * D);
  bf16x8 af[4];
#pragma unroll
  for (int kt = 0; kt < 4; ++kt) {
    u16x8 v = tg8[kt * 4 + lg];
    int c0 = (kt * 4 + lg) * 8;
    f32x4 a0 = *(const f32x4*)&stats[c0];
    f32x4 a1 = *(const f32x4*)&stats[c0 + 4];
    f32x4 b0 = *(const f32x4*)&stats[D + c0];
    f32x4 b1v = *(const f32x4*)&stats[D + c0 + 4];
    u16x8 o;
    o[0] = f2bf(fmaxf(bf2f(v[0]) * a0[0] + b0[0], 0.f));
    o[1] = f2bf(fmaxf(bf2f(v[1]) * a0[1] + b0[1], 0.f));
    o[2] = f2bf(fmaxf(bf2f(v[2]) * a0[2] + b0[2], 0.f));
    o[3] = f2bf(fmaxf(bf2f(v[3]) * a0[3] + b0[3], 0.f));
    o[4] = f2bf(fmaxf(bf2f(v[4]) * a1[0] + b1v[0], 0.f));
    o[5] = f2bf(fmaxf(bf2f(v[5]) * a1[1] + b1v[1], 0.f));
    o[6] = f2bf(fmaxf(bf2f(v[6]) * a1[2] + b1v[2], 0.f));
    o[7] = f2bf(fmaxf(bf2f(v[7]) * a1[3] + b1v[3], 0.f));
    af[kt] = *(bf16x8*)&o;
  }
  __syncthreads();  // W staged
  f32x4 acc[8];
#pragma unroll
  for (int c = 0; c < 8; ++c) { float bv = bias[c * 16 + lm]; acc[c] = (f32x4){bv, bv, bv, bv}; }
#pragma unroll
  for (int kt = 0; kt < 4; ++kt) {
    int koff = kt * 64 + lg * 16;
#pragma unroll
    for (int c = 0; c < 8; ++c) {
      int nn = c * 16 + lm;
      bf16x8 bfr = *(const bf16x8*)((const char*)wl + nn * 256 + (koff ^ ((nn & 7) << 4)));
      acc[c] = __builtin_amdgcn_mfma_f32_16x16x32_bf16(af[kt], bfr, acc[c], 0, 0, 0);
    }
  }
  __syncthreads();  // wl free -> out
#pragma unroll
  for (int c = 0; c < 8; ++c)
#pragma unroll
    for (int r = 0; r < 4; ++r)
      outbuf[(16 * w + 4 * lg + r) * D + c * 16 + lm] = acc[c][r];
  __syncthreads();
}

// layers 0..2: h_l = relu(bn(t)) @ W2 + b2 (bf16, write-only)
__global__ __launch_bounds__(256) void k_gemm2(const unsigned short* __restrict__ t,
                                               const unsigned short* __restrict__ wt,
                                               const float* __restrict__ bias,
                                               const float* __restrict__ stats,
                                               unsigned short* __restrict__ h, int N) {
  __shared__ union { unsigned short wl[D * D]; float out[64 * D]; } uB;
  int tx = threadIdx.x;
  int r0 = blockIdx.x * 64;
  gemm2_core(t, wt, bias, stats, uB.wl, uB.out, r0);
  int tc = tx & 31, tr = tx >> 5;
#pragma unroll
  for (int i = 0; i < 8; ++i) {
    int row = i * 8 + tr;
    int gr = r0 + row;
    if (gr < N) {
      f32x4 v = *(f32x4*)&uB.out[row * D + tc * 4];
      u16x4 hb; hb[0] = f2bf(v[0]); hb[1] = f2bf(v[1]); hb[2] = f2bf(v[2]); hb[3] = f2bf(v[3]);
      *(u16x4*)(h + (size_t)gr * D + tc * 4) = hb;
    }
  }
}

// layer 3: node_pool = h0+h1+h2+h3 (h3 in-register fp32, never stored)
__global__ __launch_bounds__(256) void k_gemm2_last(const unsigned short* __restrict__ t,
                                                    const unsigned short* __restrict__ wt,
                                                    const float* __restrict__ bias,
                                                    const float* __restrict__ stats,
                                                    const unsigned short* __restrict__ h0,
                                                    const unsigned short* __restrict__ h1,
                                                    const unsigned short* __restrict__ h2,
                                                    float* __restrict__ np, int N) {
  __shared__ union { unsigned short wl[D * D]; float out[64 * D]; } uB;
  int tx = threadIdx.x;
  int r0 = blockIdx.x * 64;
  gemm2_core(t, wt, bias, stats, uB.wl, uB.out, r0);
  int tc = tx & 31, tr = tx >> 5;
#pragma unroll
  for (int i = 0; i < 8; ++i) {
    int row = i * 8 + tr;
    int gr = r0 + row;
    if (gr < N) {
      f32x4 v = *(f32x4*)&uB.out[row * D + tc * 4];
      size_t o4 = (size_t)gr * D + tc * 4;
      u16x4 a = *(const u16x4*)(h0 + o4);
      u16x4 b = *(const u16x4*)(h1 + o4);
      u16x4 cc = *(const u16x4*)(h2 + o4);
      f32x4 o;
#pragma unroll
      for (int k = 0; k < 4; ++k)
        o[k] = v[k] + (bf2f(a[k]) + bf2f(b[k])) + bf2f(cc[k]);
      *(f32x4*)(np + o4) = o;
    }
  }
}

// ---------------- pooling ----------------
__global__ __launch_bounds__(256) void k_gpool(const float* __restrict__ np,
                                               const int* __restrict__ bound,
                                               float* __restrict__ gp) {
  __shared__ float red[8 * D];
  int g = blockIdx.x;
  int s = bound[g], e = bound[g + 1];
  int tc = threadIdx.x & 31, tr = threadIdx.x >> 5;
  f32x4 a = {0.f, 0.f, 0.f, 0.f};
  for (int r = s + tr; r < e; r += 8)
    a += *(const f32x4*)(np + (size_t)r * D + tc * 4);
  *(f32x4*)&red[tr * D + tc * 4] = a;
  __syncthreads();
  if (threadIdx.x < D) {
    float v = 0.f;
#pragma unroll
    for (int j = 0; j < 8; ++j) v += red[j * D + threadIdx.x];
    float c = (float)(e - s);
    gp[(size_t)g * D + threadIdx.x] = v / fmaxf(c, 1.f);
  }
}

// ---------------- launch ----------------
extern "C" void kernel_launch(void* const* d_in, const int* in_sizes, int n_in,
                              void* d_out, int out_size, void* d_ws,
                              size_t ws_size, hipStream_t stream) {
  const float* x = (const float*)d_in[0];
  const int* ei = (const int*)d_in[1];
  const int* batch = (const int*)d_in[2];
  const float* W1 = (const float*)d_in[3];
  const float* b1 = (const float*)d_in[4];
  const float* gamma = (const float*)d_in[5];
  const float* beta = (const float*)d_in[6];
  const float* W2 = (const float*)d_in[7];
  const float* b2 = (const float*)d_in[8];
  int N = in_sizes[0] / D;
  int E = in_sizes[1] / 2;
  int Npad = (N + 63) & ~63;
  int gb = Npad / 64;
  int B = (E + EPB - 1) / EPB;
  int nbin = (N + 255) / 256;
  int M = nbin * B;

  float* out = (float*)d_out;
  float* node_pool = out;
  float* g_pool = out + (size_t)N * D;

  char* wp = (char*)d_ws;
  unsigned short* hx = (unsigned short*)wp;   wp += (size_t)Npad * D * 2;
  unsigned short* t = (unsigned short*)wp;    wp += (size_t)Npad * D * 2;
  unsigned short* hbuf[3];
  for (int l = 0; l < 3; ++l) { hbuf[l] = (unsigned short*)wp; wp += (size_t)Npad * D * 2; }
  unsigned short* wt = (unsigned short*)wp;   wp += (size_t)8 * D * D * 2;
  float* partials = (float*)wp;               wp += (size_t)gb * 256 * 4;
  float* partial2 = (float*)wp;               wp += (size_t)64 * 256 * 4;
  float* stats = (float*)wp;                  wp += (size_t)2 * D * 4;
  int* bound = (int*)wp;                      wp += (size_t)(GNUM + 4) * 4;
  int* ctr = (int*)wp;                        wp += (size_t)4 * 4;
  int* rowptr = (int*)wp;                     wp += (size_t)(N + 1) * 4;
  int* perm = (int*)wp;                       wp += (size_t)Npad * 4;
  int* hist = (int*)wp;                       wp += (size_t)SH_MAX * 4;
  int* off = (int*)wp;                        wp += (size_t)SH_MAX * 4;
  int* col = (int*)wp;                        wp += (size_t)E * 4;
  int2* sorted = (int2*)wp;                   wp += (size_t)E * 8;

  k_prep_w<<<8, 256, 0, stream>>>(W1, W2, wt);
  k_prep_x<<<(N * 32 + 255) / 256, 256, 0, stream>>>(x, hx, N * 32);
  k_hist<<<B, 256, 0, stream>>>(ei, E, B, nbin, hist);
  k_hscan<<<1, 1024, 0, stream>>>(hist, M, off, rowptr, N, E, batch, bound, ctr);
  k_scatter<<<B, 256, 0, stream>>>(ei, E, B, nbin, off, sorted);
  k_build<<<nbin, 256, 0, stream>>>(sorted, off, B, nbin, E, N, rowptr, col);
  k_perm<<<gb, 64, 0, stream>>>(rowptr, N, perm);

  for (int ll = 0; ll < LNUM; ++ll) {
    const unsigned short* hin = (ll == 0) ? hx : hbuf[ll - 1];
    k_layer1<<<gb, 256, 0, stream>>>(hin, rowptr, col, perm, wt + (size_t)ll * D * D,
                                     b1 + (size_t)ll * D, t, partials, N);
    k_red1fin<<<64, 256, 0, stream>>>(partials, gb, partial2, gamma + (size_t)ll * D,
                                      beta + (size_t)ll * D, stats, N, ctr);
    if (ll < LNUM - 1) {
      k_gemm2<<<gb, 256, 0, stream>>>(t, wt + (size_t)(LNUM + ll) * D * D,
                                      b2 + (size_t)ll * D, stats, hbuf[ll], N);
    } else {
      k_gemm2_last<<<gb, 256, 0, stream>>>(t, wt + (size_t)(LNUM + ll) * D * D,
                                           b2 + (size_t)ll * D, stats,
                                           hbuf[0], hbuf[1], hbuf[2], node_pool, N);
    }
  }
  k_gpool<<<GNUM, 256, 0, stream>>>(node_pool, bound, g_pool);
}

// Round 14
// 388.133 us; speedup vs baseline: 1.0525x; 1.0525x over previous
//
#include <hip/hip_runtime.h>

#define D 128
#define GNUM 64
#define LNUM 4
#define BN_EPS 1e-5f
#define EPB 16384          // edges per hist/scatter block
#define SH_MAX 12544       // max NBIN*B the one-block scan supports

typedef short bf16x8 __attribute__((ext_vector_type(8)));       // 8 bf16 = 4 VGPR
typedef float f32x4 __attribute__((ext_vector_type(4)));
typedef unsigned short u16x8 __attribute__((ext_vector_type(8)));
typedef unsigned short u16x4 __attribute__((ext_vector_type(4)));

__device__ __forceinline__ float bf2f(unsigned short u) {
  union { unsigned int i; float f; } v; v.i = ((unsigned int)u) << 16; return v.f;
}
__device__ __forceinline__ unsigned short f2bf(float f) {
  union { float f; unsigned int i; } v; v.f = f;
  unsigned int b = v.i;
  return (unsigned short)((b + 0x7FFFu + ((b >> 16) & 1u)) >> 16);
}

// Stage one 32KB pre-swizzled W tile: direct global->LDS DMA.
// LDS dest = wave-uniform base + lane*16 (HW pattern); global src per-lane.
__device__ __forceinline__ void stage_w_dma(const unsigned short* wsw,
                                            unsigned short* wl, int tx) {
  int wv = tx >> 6, ln = tx & 63;
#pragma unroll
  for (int i = 0; i < 8; ++i) {
    int base_chunk = wv * 64 + i * 256;   // wave-uniform u16x8 index
    __builtin_amdgcn_global_load_lds(
        (const __attribute__((address_space(1))) unsigned int*)(wsw + (size_t)(base_chunk + ln) * 8),
        (__attribute__((address_space(3))) unsigned int*)(wl + (size_t)base_chunk * 8),
        16, 0, 0);
  }
}

// ---------------- CSR build: atomic-free binned counting sort ----------------
__global__ __launch_bounds__(256) void k_hist(const int* __restrict__ ei, int E,
                                              int B, int nbin, int* __restrict__ hist) {
  __shared__ int lh[256];
  int b = blockIdx.x, tx = threadIdx.x;
  lh[tx] = 0;
  __syncthreads();
  int s = b * EPB, e = min(s + EPB, E);
  for (int j = s + tx; j < e; j += 256) atomicAdd(&lh[ei[(size_t)E + j] >> 8], 1);
  __syncthreads();
  if (tx < nbin) hist[tx * B + b] = lh[tx];
}

__global__ __launch_bounds__(1024) void k_hscan(const int* __restrict__ hist, int M,
                                                int* __restrict__ off,
                                                int* __restrict__ rowptr, int N, int E) {
  __shared__ int sh[SH_MAX];
  __shared__ int sh2[1024];
  int tx = threadIdx.x;
  int chunk = (M + 1023) / 1024;
  for (int i = 0; i < chunk; ++i) {
    int idx = tx * chunk + i;
    sh[idx] = (idx < M) ? hist[idx] : 0;
  }
  __syncthreads();
  int s = 0;
  for (int i = 0; i < chunk; ++i) s += sh[tx * chunk + i];
  sh2[tx] = s;
  __syncthreads();
  for (int o = 1; o < 1024; o <<= 1) {
    int u = (tx >= o) ? sh2[tx - o] : 0;
    __syncthreads();
    sh2[tx] += u;
    __syncthreads();
  }
  int run = (tx == 0) ? 0 : sh2[tx - 1];
  for (int i = 0; i < chunk; ++i) {
    int idx = tx * chunk + i;
    if (idx < M) { int v = sh[idx]; off[idx] = run; run += v; }
  }
  if (tx == 0) rowptr[N] = E;
}

__global__ __launch_bounds__(256) void k_scatter(const int* __restrict__ ei, int E,
                                                 int B, int nbin,
                                                 const int* __restrict__ off,
                                                 int2* __restrict__ sorted) {
  __shared__ int cur[256];
  int b = blockIdx.x, tx = threadIdx.x;
  if (tx < nbin) cur[tx] = off[tx * B + b];
  __syncthreads();
  int s = b * EPB, e = min(s + EPB, E);
  for (int j = s + tx; j < e; j += 256) {
    int d = ei[(size_t)E + j];
    int sc = ei[j];
    int p = atomicAdd(&cur[d >> 8], 1);
    sorted[p] = make_int2(d, sc);
  }
}

__global__ __launch_bounds__(256) void k_build(const int2* __restrict__ sorted,
                                               const int* __restrict__ off,
                                               int B, int nbin, int E, int N,
                                               int* __restrict__ rowptr,
                                               int* __restrict__ col) {
  __shared__ int cnt[256], excl[256], cur[256];
  int beta = blockIdx.x, tx = threadIdx.x;
  int s = off[beta * B];
  int e = (beta + 1 < nbin) ? off[(beta + 1) * B] : E;
  cnt[tx] = 0;
  __syncthreads();
  for (int j = s + tx; j < e; j += 256) atomicAdd(&cnt[sorted[j].x & 255], 1);
  __syncthreads();
  int v = cnt[tx];
  excl[tx] = v;
  __syncthreads();
  for (int o = 1; o < 256; o <<= 1) {
    int u = (tx >= o) ? excl[tx - o] : 0;
    __syncthreads();
    excl[tx] += u;
    __syncthreads();
  }
  int ex = excl[tx] - v;
  int n = beta * 256 + tx;
  if (n < N) rowptr[n] = s + ex;
  cur[tx] = s + ex;
  __syncthreads();
  for (int j = s + tx; j < e; j += 256) {
    int2 p = sorted[j];
    int q = atomicAdd(&cur[p.x & 255], 1);
    col[q] = p.y;
  }
}

__global__ void k_bounds(const int* __restrict__ batch, int N, int* __restrict__ bound) {
  int g = threadIdx.x;
  if (g > GNUM) return;
  int lo = 0, hi = N;
  while (lo < hi) { int mid = (lo + hi) >> 1; if (batch[mid] < g) lo = mid + 1; else hi = mid; }
  bound[g] = lo;
}

// per-64-tile degree rank: perm[r0+rank] = local row (pads rank first)
__global__ __launch_bounds__(64) void k_perm(const int* __restrict__ rowptr, int N,
                                             int* __restrict__ perm) {
  __shared__ int degs[64];
  int r0 = blockIdx.x * 64;
  int i = threadIdx.x;
  int n = r0 + i;
  int d = (n < N) ? (rowptr[n + 1] - rowptr[n]) : -1;
  degs[i] = d;
  __syncthreads();
  int rank = 0;
#pragma unroll
  for (int j = 0; j < 64; ++j) {
    int dj = degs[j];
    if (dj < d || (dj == d && j < i)) ++rank;
  }
  perm[r0 + rank] = i;
}

// ---------------- prep ----------------
__global__ void k_prep_x(const float* __restrict__ x, unsigned short* __restrict__ hx, int total4) {
  int i = blockIdx.x * 256 + threadIdx.x;
  if (i < total4) {
    f32x4 v = ((const f32x4*)x)[i];
    u16x4 o; o[0] = f2bf(v[0]); o[1] = f2bf(v[1]); o[2] = f2bf(v[2]); o[3] = f2bf(v[3]);
    ((u16x4*)hx)[i] = o;
  }
}

// W -> bf16, transposed AND pre-swizzled to the exact LDS image:
// element (n,k) -> n*128 + ((((k>>3) ^ (n&7)) << 3) | (k&7))
__global__ __launch_bounds__(256) void k_prep_w(const float* __restrict__ W1,
                                                const float* __restrict__ W2,
                                                unsigned short* __restrict__ wt) {
  int l = blockIdx.x;
  const float* W = (l < LNUM) ? (W1 + (size_t)l * D * D) : (W2 + (size_t)(l - LNUM) * D * D);
  unsigned short* o = wt + (size_t)l * D * D;
#pragma unroll
  for (int i = 0; i < 64; ++i) {
    int idx = threadIdx.x + 256 * i;       // idx = k*128 + n
    int k = idx >> 7, n = idx & 127;
    int kd = (((k >> 3) ^ (n & 7)) << 3) | (k & 7);
    o[n * D + kd] = f2bf(W[idx]);
  }
}

// ---------------- fused layer-1 (round-12 gather) + DMA W staging ----------------
__global__ __launch_bounds__(256, 3) void k_layer1(const unsigned short* __restrict__ hin,
                                                const int* __restrict__ rowptr,
                                                const int* __restrict__ col,
                                                const int* __restrict__ perm,
                                                const unsigned short* __restrict__ wt,
                                                const float* __restrict__ bias,
                                                unsigned short* __restrict__ t,
                                                float* __restrict__ partials, int N) {
  __shared__ union { unsigned short wl[D * D]; float out[64 * D]; } uB;  // 32KB
  __shared__ float red[2 * 8 * D];                                      // 8KB
  int tx = threadIdx.x;
  int r0 = blockIdx.x * 64;
  stage_w_dma(wt, uB.wl, tx);    // async DMA; __syncthreads below drains it
  int l = tx & 63, w = tx >> 6;
  int lm = l & 15, lg = l >> 4;
  int lr = perm[r0 + 16 * w + lm];
  int pr0 = perm[r0 + 16 * w + 4 * lg + 0];
  int pr1 = perm[r0 + 16 * w + 4 * lg + 1];
  int pr2 = perm[r0 + 16 * w + 4 * lg + 2];
  int pr3 = perm[r0 + 16 * w + 4 * lg + 3];
  int n = r0 + lr;
  const u16x8* h8 = (const u16x8*)hin;
  f32x4 sA[4] = {{0.f,0.f,0.f,0.f},{0.f,0.f,0.f,0.f},{0.f,0.f,0.f,0.f},{0.f,0.f,0.f,0.f}};
  f32x4 sB[4] = {{0.f,0.f,0.f,0.f},{0.f,0.f,0.f,0.f},{0.f,0.f,0.f,0.f},{0.f,0.f,0.f,0.f}};
  int e0 = 0, e1 = 0;
  if (n < N) { e0 = rowptr[n]; e1 = rowptr[n + 1]; }
  int j = e0;
  for (; j + 3 < e1; j += 4) {               // 16 x 16B loads in flight
    size_t a0i = (size_t)col[j] * 16 + lg;
    size_t a1i = (size_t)col[j + 1] * 16 + lg;
    size_t a2i = (size_t)col[j + 2] * 16 + lg;
    size_t a3i = (size_t)col[j + 3] * 16 + lg;
    u16x8 u00 = h8[a0i], u01 = h8[a0i + 4], u02 = h8[a0i + 8], u03 = h8[a0i + 12];
    u16x8 u10 = h8[a1i], u11 = h8[a1i + 4], u12 = h8[a1i + 8], u13 = h8[a1i + 12];
    u16x8 u20 = h8[a2i], u21 = h8[a2i + 4], u22 = h8[a2i + 8], u23 = h8[a2i + 12];
    u16x8 u30 = h8[a3i], u31 = h8[a3i + 4], u32 = h8[a3i + 8], u33 = h8[a3i + 12];
#pragma unroll
    for (int k = 0; k < 4; ++k) {
      sA[0][k] += (bf2f(u00[k]) + bf2f(u10[k])) + (bf2f(u20[k]) + bf2f(u30[k]));
      sB[0][k] += (bf2f(u00[4+k]) + bf2f(u10[4+k])) + (bf2f(u20[4+k]) + bf2f(u30[4+k]));
      sA[1][k] += (bf2f(u01[k]) + bf2f(u11[k])) + (bf2f(u21[k]) + bf2f(u31[k]));
      sB[1][k] += (bf2f(u01[4+k]) + bf2f(u11[4+k])) + (bf2f(u21[4+k]) + bf2f(u31[4+k]));
      sA[2][k] += (bf2f(u02[k]) + bf2f(u12[k])) + (bf2f(u22[k]) + bf2f(u32[k]));
      sB[2][k] += (bf2f(u02[4+k]) + bf2f(u12[4+k])) + (bf2f(u22[4+k]) + bf2f(u32[4+k]));
      sA[3][k] += (bf2f(u03[k]) + bf2f(u13[k])) + (bf2f(u23[k]) + bf2f(u33[k]));
      sB[3][k] += (bf2f(u03[4+k]) + bf2f(u13[4+k])) + (bf2f(u23[4+k]) + bf2f(u33[4+k]));
    }
  }
  for (; j < e1; ++j) {
    size_t a0i = (size_t)col[j] * 16 + lg;
    u16x8 u00 = h8[a0i], u01 = h8[a0i + 4], u02 = h8[a0i + 8], u03 = h8[a0i + 12];
#pragma unroll
    for (int k = 0; k < 4; ++k) {
      sA[0][k] += bf2f(u00[k]);  sB[0][k] += bf2f(u00[4+k]);
      sA[1][k] += bf2f(u01[k]);  sB[1][k] += bf2f(u01[4+k]);
      sA[2][k] += bf2f(u02[k]);  sB[2][k] += bf2f(u02[4+k]);
      sA[3][k] += bf2f(u03[k]);  sB[3][k] += bf2f(u03[4+k]);
    }
  }
  bf16x8 af[4];
  if (n < N) {
    float inv = (e1 > e0) ? 1.f / (float)(e1 - e0) : 0.f;
#pragma unroll
    for (int kt = 0; kt < 4; ++kt) {
      u16x8 hv = h8[(size_t)n * 16 + kt * 4 + lg];
      u16x8 o;
#pragma unroll
      for (int k = 0; k < 4; ++k) {
        o[k] = f2bf(bf2f(hv[k]) + sA[kt][k] * inv);
        o[4 + k] = f2bf(bf2f(hv[4 + k]) + sB[kt][k] * inv);
      }
      af[kt] = *(bf16x8*)&o;
    }
  } else {
#pragma unroll
    for (int kt = 0; kt < 4; ++kt) af[kt] = (bf16x8){0,0,0,0,0,0,0,0};
  }
  __syncthreads();   // drains DMA (vmcnt) + all lanes ready
  f32x4 acc[8];
#pragma unroll
  for (int cc = 0; cc < 8; ++cc) { float bv = bias[cc * 16 + lm]; acc[cc] = (f32x4){bv, bv, bv, bv}; }
#pragma unroll
  for (int kt = 0; kt < 4; ++kt) {
    int koff = kt * 64 + lg * 16;
#pragma unroll
    for (int cc = 0; cc < 8; ++cc) {
      int nn = cc * 16 + lm;
      bf16x8 bfr = *(const bf16x8*)((const char*)uB.wl + nn * 256 + (koff ^ ((nn & 7) << 4)));
      acc[cc] = __builtin_amdgcn_mfma_f32_16x16x32_bf16(af[kt], bfr, acc[cc], 0, 0, 0);
    }
  }
  __syncthreads();  // wl free -> out
#pragma unroll
  for (int cc = 0; cc < 8; ++cc) {          // write via perm: natural row order
    uB.out[pr0 * D + cc * 16 + lm] = acc[cc][0];
    uB.out[pr1 * D + cc * 16 + lm] = acc[cc][1];
    uB.out[pr2 * D + cc * 16 + lm] = acc[cc][2];
    uB.out[pr3 * D + cc * 16 + lm] = acc[cc][3];
  }
  __syncthreads();
  int tc = tx & 31, tr = tx >> 5;
  f32x4 s = {0.f, 0.f, 0.f, 0.f}, q = {0.f, 0.f, 0.f, 0.f};
#pragma unroll
  for (int i = 0; i < 8; ++i) {
    int rr = i * 8 + tr;
    f32x4 v = *(f32x4*)&uB.out[rr * D + tc * 4];
    u16x4 o; o[0] = f2bf(v[0]); o[1] = f2bf(v[1]); o[2] = f2bf(v[2]); o[3] = f2bf(v[3]);
    *(u16x4*)(t + (size_t)(r0 + rr) * D + tc * 4) = o;
    if (r0 + rr < N) { s += v; q += v * v; }
  }
  *(f32x4*)&red[tr * D + tc * 4] = s;
  *(f32x4*)&red[8 * D + tr * D + tc * 4] = q;
  __syncthreads();
  int colx = tx & 127, which = tx >> 7;
  float S = 0.f;
#pragma unroll
  for (int jj = 0; jj < 8; ++jj) S += red[which * 8 * D + jj * D + colx];
  partials[(size_t)blockIdx.x * 256 + tx] = S;
}

// reduce stage 1
__global__ __launch_bounds__(256) void k_red1(const float* __restrict__ partials, int NB,
                                              float* __restrict__ partial2) {
  int tx = threadIdx.x;
  float S = 0.f;
  for (int b = blockIdx.x; b < NB; b += 64) S += partials[(size_t)b * 256 + tx];
  partial2[(size_t)blockIdx.x * 256 + tx] = S;
}

__global__ __launch_bounds__(256) void k_finalize(const float* __restrict__ partial2,
                                                  const float* __restrict__ gamma,
                                                  const float* __restrict__ beta,
                                                  float* __restrict__ stats, int N) {
  __shared__ float sh[256];
  int tx = threadIdx.x;
  float S = 0.f;
#pragma unroll 8
  for (int b = 0; b < 64; ++b) S += partial2[(size_t)b * 256 + tx];
  sh[tx] = S;
  __syncthreads();
  if (tx < D) {
    float mu = sh[tx] / (float)N;
    float var = sh[D + tx] / (float)N - mu * mu;
    float rstd = rsqrtf(fmaxf(var, 0.f) + BN_EPS);
    float A = gamma[tx] * rstd;
    stats[tx] = A;
    stats[D + tx] = beta[tx] - mu * A;
  }
}

// ---------------- GEMM2 core: register-direct A + DMA W staging ----------------
__device__ __forceinline__ void gemm2_core(const unsigned short* t,
                                           const unsigned short* wt,
                                           const float* bias, const float* stats,
                                           unsigned short* wl, float* outbuf, int r0) {
  int tx = threadIdx.x;
  stage_w_dma(wt, wl, tx);       // async DMA; __syncthreads below drains it
  int l = tx & 63, w = tx >> 6;
  int lm = l & 15, lg = l >> 4;
  int row = 16 * w + lm;
  const u16x8* tg8 = (const u16x8*)(t + (size_t)(r0 + row) * D);
  bf16x8 af[4];
#pragma unroll
  for (int kt = 0; kt < 4; ++kt) {
    u16x8 v = tg8[kt * 4 + lg];
    int c0 = (kt * 4 + lg) * 8;
    f32x4 a0 = *(const f32x4*)&stats[c0];
    f32x4 a1 = *(const f32x4*)&stats[c0 + 4];
    f32x4 b0 = *(const f32x4*)&stats[D + c0];
    f32x4 b1v = *(const f32x4*)&stats[D + c0 + 4];
    u16x8 o;
    o[0] = f2bf(fmaxf(bf2f(v[0]) * a0[0] + b0[0], 0.f));
    o[1] = f2bf(fmaxf(bf2f(v[1]) * a0[1] + b0[1], 0.f));
    o[2] = f2bf(fmaxf(bf2f(v[2]) * a0[2] + b0[2], 0.f));
    o[3] = f2bf(fmaxf(bf2f(v[3]) * a0[3] + b0[3], 0.f));
    o[4] = f2bf(fmaxf(bf2f(v[4]) * a1[0] + b1v[0], 0.f));
    o[5] = f2bf(fmaxf(bf2f(v[5]) * a1[1] + b1v[1], 0.f));
    o[6] = f2bf(fmaxf(bf2f(v[6]) * a1[2] + b1v[2], 0.f));
    o[7] = f2bf(fmaxf(bf2f(v[7]) * a1[3] + b1v[3], 0.f));
    af[kt] = *(bf16x8*)&o;
  }
  __syncthreads();  // drains DMA
  f32x4 acc[8];
#pragma unroll
  for (int c = 0; c < 8; ++c) { float bv = bias[c * 16 + lm]; acc[c] = (f32x4){bv, bv, bv, bv}; }
#pragma unroll
  for (int kt = 0; kt < 4; ++kt) {
    int koff = kt * 64 + lg * 16;
#pragma unroll
    for (int c = 0; c < 8; ++c) {
      int nn = c * 16 + lm;
      bf16x8 bfr = *(const bf16x8*)((const char*)wl + nn * 256 + (koff ^ ((nn & 7) << 4)));
      acc[c] = __builtin_amdgcn_mfma_f32_16x16x32_bf16(af[kt], bfr, acc[c], 0, 0, 0);
    }
  }
  __syncthreads();  // wl free -> out
#pragma unroll
  for (int c = 0; c < 8; ++c)
#pragma unroll
    for (int r = 0; r < 4; ++r)
      outbuf[(16 * w + 4 * lg + r) * D + c * 16 + lm] = acc[c][r];
  __syncthreads();
}

// layers 0..2: h_l = relu(bn(t)) @ W2 + b2 (bf16, write-only)
__global__ __launch_bounds__(256) void k_gemm2(const unsigned short* __restrict__ t,
                                               const unsigned short* __restrict__ wt,
                                               const float* __restrict__ bias,
                                               const float* __restrict__ stats,
                                               unsigned short* __restrict__ h, int N) {
  __shared__ union { unsigned short wl[D * D]; float out[64 * D]; } uB;
  int tx = threadIdx.x;
  int r0 = blockIdx.x * 64;
  gemm2_core(t, wt, bias, stats, uB.wl, uB.out, r0);
  int tc = tx & 31, tr = tx >> 5;
#pragma unroll
  for (int i = 0; i < 8; ++i) {
    int row = i * 8 + tr;
    int gr = r0 + row;
    if (gr < N) {
      f32x4 v = *(f32x4*)&uB.out[row * D + tc * 4];
      u16x4 hb; hb[0] = f2bf(v[0]); hb[1] = f2bf(v[1]); hb[2] = f2bf(v[2]); hb[3] = f2bf(v[3]);
      *(u16x4*)(h + (size_t)gr * D + tc * 4) = hb;
    }
  }
}

// layer 3: node_pool = h0+h1+h2+h3 (h3 in-register fp32, never stored)
__global__ __launch_bounds__(256) void k_gemm2_last(const unsigned short* __restrict__ t,
                                                    const unsigned short* __restrict__ wt,
                                                    const float* __restrict__ bias,
                                                    const float* __restrict__ stats,
                                                    const unsigned short* __restrict__ h0,
                                                    const unsigned short* __restrict__ h1,
                                                    const unsigned short* __restrict__ h2,
                                                    float* __restrict__ np, int N) {
  __shared__ union { unsigned short wl[D * D]; float out[64 * D]; } uB;
  int tx = threadIdx.x;
  int r0 = blockIdx.x * 64;
  gemm2_core(t, wt, bias, stats, uB.wl, uB.out, r0);
  int tc = tx & 31, tr = tx >> 5;
#pragma unroll
  for (int i = 0; i < 8; ++i) {
    int row = i * 8 + tr;
    int gr = r0 + row;
    if (gr < N) {
      f32x4 v = *(f32x4*)&uB.out[row * D + tc * 4];
      size_t o4 = (size_t)gr * D + tc * 4;
      u16x4 a = *(const u16x4*)(h0 + o4);
      u16x4 b = *(const u16x4*)(h1 + o4);
      u16x4 cc = *(const u16x4*)(h2 + o4);
      f32x4 o;
#pragma unroll
      for (int k = 0; k < 4; ++k)
        o[k] = v[k] + (bf2f(a[k]) + bf2f(b[k])) + bf2f(cc[k]);
      *(f32x4*)(np + o4) = o;
    }
  }
}

// ---------------- pooling ----------------
__global__ __launch_bounds__(256) void k_gpool(const float* __restrict__ np,
                                               const int* __restrict__ bound,
                                               float* __restrict__ gp) {
  __shared__ float red[8 * D];
  int g = blockIdx.x;
  int s = bound[g], e = bound[g + 1];
  int tc = threadIdx.x & 31, tr = threadIdx.x >> 5;
  f32x4 a = {0.f, 0.f, 0.f, 0.f};
  for (int r = s + tr; r < e; r += 8)
    a += *(const f32x4*)(np + (size_t)r * D + tc * 4);
  *(f32x4*)&red[tr * D + tc * 4] = a;
  __syncthreads();
  if (threadIdx.x < D) {
    float v = 0.f;
#pragma unroll
    for (int j = 0; j < 8; ++j) v += red[j * D + threadIdx.x];
    float c = (float)(e - s);
    gp[(size_t)g * D + threadIdx.x] = v / fmaxf(c, 1.f);
  }
}

// ---------------- launch ----------------
extern "C" void kernel_launch(void* const* d_in, const int* in_sizes, int n_in,
                              void* d_out, int out_size, void* d_ws,
                              size_t ws_size, hipStream_t stream) {
  const float* x = (const float*)d_in[0];
  const int* ei = (const int*)d_in[1];
  const int* batch = (const int*)d_in[2];
  const float* W1 = (const float*)d_in[3];
  const float* b1 = (const float*)d_in[4];
  const float* gamma = (const float*)d_in[5];
  const float* beta = (const float*)d_in[6];
  const float* W2 = (const float*)d_in[7];
  const float* b2 = (const float*)d_in[8];
  int N = in_sizes[0] / D;
  int E = in_sizes[1] / 2;
  int Npad = (N + 63) & ~63;
  int gb = Npad / 64;
  int B = (E + EPB - 1) / EPB;
  int nbin = (N + 255) / 256;
  int M = nbin * B;

  float* out = (float*)d_out;
  float* node_pool = out;
  float* g_pool = out + (size_t)N * D;

  char* wp = (char*)d_ws;
  unsigned short* hx = (unsigned short*)wp;   wp += (size_t)Npad * D * 2;
  unsigned short* t = (unsigned short*)wp;    wp += (size_t)Npad * D * 2;
  unsigned short* hbuf[3];
  for (int l = 0; l < 3; ++l) { hbuf[l] = (unsigned short*)wp; wp += (size_t)Npad * D * 2; }
  unsigned short* wt = (unsigned short*)wp;   wp += (size_t)8 * D * D * 2;
  float* partials = (float*)wp;               wp += (size_t)gb * 256 * 4;
  float* partial2 = (float*)wp;               wp += (size_t)64 * 256 * 4;
  float* stats = (float*)wp;                  wp += (size_t)2 * D * 4;
  int* bound = (int*)wp;                      wp += (size_t)(GNUM + 4) * 4;
  int* rowptr = (int*)wp;                     wp += (size_t)(N + 1) * 4;
  int* perm = (int*)wp;                       wp += (size_t)Npad * 4;
  int* hist = (int*)wp;                       wp += (size_t)SH_MAX * 4;
  int* off = (int*)wp;                        wp += (size_t)SH_MAX * 4;
  int* col = (int*)wp;                        wp += (size_t)E * 4;
  int2* sorted = (int2*)wp;                   wp += (size_t)E * 8;

  k_prep_w<<<8, 256, 0, stream>>>(W1, W2, wt);
  k_prep_x<<<(N * 32 + 255) / 256, 256, 0, stream>>>(x, hx, N * 32);
  k_hist<<<B, 256, 0, stream>>>(ei, E, B, nbin, hist);
  k_hscan<<<1, 1024, 0, stream>>>(hist, M, off, rowptr, N, E);
  k_scatter<<<B, 256, 0, stream>>>(ei, E, B, nbin, off, sorted);
  k_build<<<nbin, 256, 0, stream>>>(sorted, off, B, nbin, E, N, rowptr, col);
  k_perm<<<gb, 64, 0, stream>>>(rowptr, N, perm);
  k_bounds<<<1, 128, 0, stream>>>(batch, N, bound);

  for (int ll = 0; ll < LNUM; ++ll) {
    const unsigned short* hin = (ll == 0) ? hx : hbuf[ll - 1];
    k_layer1<<<gb, 256, 0, stream>>>(hin, rowptr, col, perm, wt + (size_t)ll * D * D,
                                     b1 + (size_t)ll * D, t, partials, N);
    k_red1<<<64, 256, 0, stream>>>(partials, gb, partial2);
    k_finalize<<<1, 256, 0, stream>>>(partial2, gamma + (size_t)ll * D,
                                      beta + (size_t)ll * D, stats, N);
    if (ll < LNUM - 1) {
      k_gemm2<<<gb, 256, 0, stream>>>(t, wt + (size_t)(LNUM + ll) * D * D,
                                      b2 + (size_t)ll * D, stats, hbuf[ll], N);
    } else {
      k_gemm2_last<<<gb, 256, 0, stream>>>(t, wt + (size_t)(LNUM + ll) * D * D,
                                           b2 + (size_t)ll * D, stats,
                                           hbuf[0], hbuf[1], hbuf[2], node_pool, N);
    }
  }
  k_gpool<<<GNUM, 256, 0, stream>>>(node_pool, bound, g_pool);
}

// Round 15
// 381.034 us; speedup vs baseline: 1.0721x; 1.0186x over previous
//
#include <hip/hip_runtime.h>

#define D 128
#define GNUM 64
#define LNUM 4
#define BN_EPS 1e-5f
#define EPB 16384          // edges per hist/scatter block
#define SH_MAX 12544       // max NBIN*B the one-block scan supports

typedef short bf16x8 __attribute__((ext_vector_type(8)));       // 8 bf16 = 4 VGPR
typedef float f32x4 __attribute__((ext_vector_type(4)));
typedef unsigned short u16x8 __attribute__((ext_vector_type(8)));
typedef unsigned short u16x4 __attribute__((ext_vector_type(4)));

__device__ __forceinline__ float bf2f(unsigned short u) {
  union { unsigned int i; float f; } v; v.i = ((unsigned int)u) << 16; return v.f;
}
__device__ __forceinline__ unsigned short f2bf(float f) {
  union { float f; unsigned int i; } v; v.f = f;
  unsigned int b = v.i;
  return (unsigned short)((b + 0x7FFFu + ((b >> 16) & 1u)) >> 16);
}

// Stage one 32KB pre-swizzled W tile: direct global->LDS DMA.
__device__ __forceinline__ void stage_w_dma(const unsigned short* wsw,
                                            unsigned short* wl, int tx) {
  int wv = tx >> 6, ln = tx & 63;
#pragma unroll
  for (int i = 0; i < 8; ++i) {
    int base_chunk = wv * 64 + i * 256;   // wave-uniform u16x8 index
    __builtin_amdgcn_global_load_lds(
        (const __attribute__((address_space(1))) unsigned int*)(wsw + (size_t)(base_chunk + ln) * 8),
        (__attribute__((address_space(3))) unsigned int*)(wl + (size_t)base_chunk * 8),
        16, 0, 0);
  }
}

// ---------------- CSR build: atomic-free binned counting sort ----------------
__global__ __launch_bounds__(256) void k_hist(const int* __restrict__ ei, int E,
                                              int B, int nbin, int* __restrict__ hist) {
  __shared__ int lh[256];
  int b = blockIdx.x, tx = threadIdx.x;
  lh[tx] = 0;
  __syncthreads();
  int s = b * EPB, e = min(s + EPB, E);
  for (int j = s + tx; j < e; j += 256) atomicAdd(&lh[ei[(size_t)E + j] >> 8], 1);
  __syncthreads();
  if (tx < nbin) hist[tx * B + b] = lh[tx];
}

__global__ __launch_bounds__(1024) void k_hscan(const int* __restrict__ hist, int M,
                                                int* __restrict__ off,
                                                int* __restrict__ rowptr, int N, int E) {
  __shared__ int sh[SH_MAX];
  __shared__ int sh2[1024];
  int tx = threadIdx.x;
  int chunk = (M + 1023) / 1024;
  for (int i = 0; i < chunk; ++i) {
    int idx = tx * chunk + i;
    sh[idx] = (idx < M) ? hist[idx] : 0;
  }
  __syncthreads();
  int s = 0;
  for (int i = 0; i < chunk; ++i) s += sh[tx * chunk + i];
  sh2[tx] = s;
  __syncthreads();
  for (int o = 1; o < 1024; o <<= 1) {
    int u = (tx >= o) ? sh2[tx - o] : 0;
    __syncthreads();
    sh2[tx] += u;
    __syncthreads();
  }
  int run = (tx == 0) ? 0 : sh2[tx - 1];
  for (int i = 0; i < chunk; ++i) {
    int idx = tx * chunk + i;
    if (idx < M) { int v = sh[idx]; off[idx] = run; run += v; }
  }
  if (tx == 0) rowptr[N] = E;
}

__global__ __launch_bounds__(256) void k_scatter(const int* __restrict__ ei, int E,
                                                 int B, int nbin,
                                                 const int* __restrict__ off,
                                                 int2* __restrict__ sorted) {
  __shared__ int cur[256];
  int b = blockIdx.x, tx = threadIdx.x;
  if (tx < nbin) cur[tx] = off[tx * B + b];
  __syncthreads();
  int s = b * EPB, e = min(s + EPB, E);
  for (int j = s + tx; j < e; j += 256) {
    int d = ei[(size_t)E + j];
    int sc = ei[j];
    int p = atomicAdd(&cur[d >> 8], 1);
    sorted[p] = make_int2(d, sc);
  }
}

__global__ __launch_bounds__(256) void k_build(const int2* __restrict__ sorted,
                                               const int* __restrict__ off,
                                               int B, int nbin, int E, int N,
                                               int* __restrict__ rowptr,
                                               int* __restrict__ col) {
  __shared__ int cnt[256], excl[256], cur[256];
  int beta = blockIdx.x, tx = threadIdx.x;
  int s = off[beta * B];
  int e = (beta + 1 < nbin) ? off[(beta + 1) * B] : E;
  cnt[tx] = 0;
  __syncthreads();
  for (int j = s + tx; j < e; j += 256) atomicAdd(&cnt[sorted[j].x & 255], 1);
  __syncthreads();
  int v = cnt[tx];
  excl[tx] = v;
  __syncthreads();
  for (int o = 1; o < 256; o <<= 1) {
    int u = (tx >= o) ? excl[tx - o] : 0;
    __syncthreads();
    excl[tx] += u;
    __syncthreads();
  }
  int ex = excl[tx] - v;
  int n = beta * 256 + tx;
  if (n < N) rowptr[n] = s + ex;
  cur[tx] = s + ex;
  __syncthreads();
  for (int j = s + tx; j < e; j += 256) {
    int2 p = sorted[j];
    int q = atomicAdd(&cur[p.x & 255], 1);
    col[q] = p.y;
  }
}

// per-64-tile degree rank (+ block 0 computes graph bounds)
__global__ __launch_bounds__(64) void k_perm(const int* __restrict__ rowptr, int N,
                                             int* __restrict__ perm,
                                             const int* __restrict__ batch,
                                             int* __restrict__ bound) {
  __shared__ int degs[64];
  int r0 = blockIdx.x * 64;
  int i = threadIdx.x;
  int n = r0 + i;
  int d = (n < N) ? (rowptr[n + 1] - rowptr[n]) : -1;
  degs[i] = d;
  if (blockIdx.x == 0) {
    for (int g = i; g <= GNUM; g += 64) {
      int lo = 0, hi = N;
      while (lo < hi) { int mid = (lo + hi) >> 1; if (batch[mid] < g) lo = mid + 1; else hi = mid; }
      bound[g] = lo;
    }
  }
  __syncthreads();
  int rank = 0;
#pragma unroll
  for (int j = 0; j < 64; ++j) {
    int dj = degs[j];
    if (dj < d || (dj == d && j < i)) ++rank;
  }
  perm[r0 + rank] = i;
}

// ---------------- prep: W (blocks 0..7) + x (remaining blocks) ----------------
__global__ __launch_bounds__(256) void k_prep(const float* __restrict__ W1,
                                              const float* __restrict__ W2,
                                              unsigned short* __restrict__ wt,
                                              const float* __restrict__ x,
                                              unsigned short* __restrict__ hx, int total4) {
  if (blockIdx.x < 8) {
    int l = blockIdx.x;
    const float* W = (l < LNUM) ? (W1 + (size_t)l * D * D) : (W2 + (size_t)(l - LNUM) * D * D);
    unsigned short* o = wt + (size_t)l * D * D;
#pragma unroll
    for (int i = 0; i < 64; ++i) {
      int idx = threadIdx.x + 256 * i;       // idx = k*128 + n
      int k = idx >> 7, n = idx & 127;
      int kd = (((k >> 3) ^ (n & 7)) << 3) | (k & 7);   // pre-swizzled LDS image
      o[n * D + kd] = f2bf(W[idx]);
    }
  } else {
    int i = (blockIdx.x - 8) * 256 + threadIdx.x;
    if (i < total4) {
      f32x4 v = ((const f32x4*)x)[i];
      u16x4 o; o[0] = f2bf(v[0]); o[1] = f2bf(v[1]); o[2] = f2bf(v[2]); o[3] = f2bf(v[3]);
      ((u16x4*)hx)[i] = o;
    }
  }
}

// ---------------- fused layer-1 (round-12 gather) + DMA W staging ----------------
__global__ __launch_bounds__(256, 3) void k_layer1(const unsigned short* __restrict__ hin,
                                                const int* __restrict__ rowptr,
                                                const int* __restrict__ col,
                                                const int* __restrict__ perm,
                                                const unsigned short* __restrict__ wt,
                                                const float* __restrict__ bias,
                                                unsigned short* __restrict__ t,
                                                float* __restrict__ partials, int N) {
  __shared__ union { unsigned short wl[D * D]; float out[64 * D]; } uB;  // 32KB
  __shared__ float red[2 * 8 * D];                                      // 8KB
  int tx = threadIdx.x;
  int r0 = blockIdx.x * 64;
  stage_w_dma(wt, uB.wl, tx);    // async DMA; __syncthreads below drains it
  int l = tx & 63, w = tx >> 6;
  int lm = l & 15, lg = l >> 4;
  int lr = perm[r0 + 16 * w + lm];
  int pr0 = perm[r0 + 16 * w + 4 * lg + 0];
  int pr1 = perm[r0 + 16 * w + 4 * lg + 1];
  int pr2 = perm[r0 + 16 * w + 4 * lg + 2];
  int pr3 = perm[r0 + 16 * w + 4 * lg + 3];
  int n = r0 + lr;
  const u16x8* h8 = (const u16x8*)hin;
  f32x4 sA[4] = {{0.f,0.f,0.f,0.f},{0.f,0.f,0.f,0.f},{0.f,0.f,0.f,0.f},{0.f,0.f,0.f,0.f}};
  f32x4 sB[4] = {{0.f,0.f,0.f,0.f},{0.f,0.f,0.f,0.f},{0.f,0.f,0.f,0.f},{0.f,0.f,0.f,0.f}};
  int e0 = 0, e1 = 0;
  if (n < N) { e0 = rowptr[n]; e1 = rowptr[n + 1]; }
  int j = e0;
  for (; j + 3 < e1; j += 4) {               // 16 x 16B loads in flight
    size_t a0i = (size_t)col[j] * 16 + lg;
    size_t a1i = (size_t)col[j + 1] * 16 + lg;
    size_t a2i = (size_t)col[j + 2] * 16 + lg;
    size_t a3i = (size_t)col[j + 3] * 16 + lg;
    u16x8 u00 = h8[a0i], u01 = h8[a0i + 4], u02 = h8[a0i + 8], u03 = h8[a0i + 12];
    u16x8 u10 = h8[a1i], u11 = h8[a1i + 4], u12 = h8[a1i + 8], u13 = h8[a1i + 12];
    u16x8 u20 = h8[a2i], u21 = h8[a2i + 4], u22 = h8[a2i + 8], u23 = h8[a2i + 12];
    u16x8 u30 = h8[a3i], u31 = h8[a3i + 4], u32 = h8[a3i + 8], u33 = h8[a3i + 12];
#pragma unroll
    for (int k = 0; k < 4; ++k) {
      sA[0][k] += (bf2f(u00[k]) + bf2f(u10[k])) + (bf2f(u20[k]) + bf2f(u30[k]));
      sB[0][k] += (bf2f(u00[4+k]) + bf2f(u10[4+k])) + (bf2f(u20[4+k]) + bf2f(u30[4+k]));
      sA[1][k] += (bf2f(u01[k]) + bf2f(u11[k])) + (bf2f(u21[k]) + bf2f(u31[k]));
      sB[1][k] += (bf2f(u01[4+k]) + bf2f(u11[4+k])) + (bf2f(u21[4+k]) + bf2f(u31[4+k]));
      sA[2][k] += (bf2f(u02[k]) + bf2f(u12[k])) + (bf2f(u22[k]) + bf2f(u32[k]));
      sB[2][k] += (bf2f(u02[4+k]) + bf2f(u12[4+k])) + (bf2f(u22[4+k]) + bf2f(u32[4+k]));
      sA[3][k] += (bf2f(u03[k]) + bf2f(u13[k])) + (bf2f(u23[k]) + bf2f(u33[k]));
      sB[3][k] += (bf2f(u03[4+k]) + bf2f(u13[4+k])) + (bf2f(u23[4+k]) + bf2f(u33[4+k]));
    }
  }
  for (; j < e1; ++j) {
    size_t a0i = (size_t)col[j] * 16 + lg;
    u16x8 u00 = h8[a0i], u01 = h8[a0i + 4], u02 = h8[a0i + 8], u03 = h8[a0i + 12];
#pragma unroll
    for (int k = 0; k < 4; ++k) {
      sA[0][k] += bf2f(u00[k]);  sB[0][k] += bf2f(u00[4+k]);
      sA[1][k] += bf2f(u01[k]);  sB[1][k] += bf2f(u01[4+k]);
      sA[2][k] += bf2f(u02[k]);  sB[2][k] += bf2f(u02[4+k]);
      sA[3][k] += bf2f(u03[k]);  sB[3][k] += bf2f(u03[4+k]);
    }
  }
  bf16x8 af[4];
  if (n < N) {
    float inv = (e1 > e0) ? 1.f / (float)(e1 - e0) : 0.f;
#pragma unroll
    for (int kt = 0; kt < 4; ++kt) {
      u16x8 hv = h8[(size_t)n * 16 + kt * 4 + lg];
      u16x8 o;
#pragma unroll
      for (int k = 0; k < 4; ++k) {
        o[k] = f2bf(bf2f(hv[k]) + sA[kt][k] * inv);
        o[4 + k] = f2bf(bf2f(hv[4 + k]) + sB[kt][k] * inv);
      }
      af[kt] = *(bf16x8*)&o;
    }
  } else {
#pragma unroll
    for (int kt = 0; kt < 4; ++kt) af[kt] = (bf16x8){0,0,0,0,0,0,0,0};
  }
  __syncthreads();   // drains DMA (vmcnt) + all lanes ready
  f32x4 acc[8];
#pragma unroll
  for (int cc = 0; cc < 8; ++cc) { float bv = bias[cc * 16 + lm]; acc[cc] = (f32x4){bv, bv, bv, bv}; }
#pragma unroll
  for (int kt = 0; kt < 4; ++kt) {
    int koff = kt * 64 + lg * 16;
#pragma unroll
    for (int cc = 0; cc < 8; ++cc) {
      int nn = cc * 16 + lm;
      bf16x8 bfr = *(const bf16x8*)((const char*)uB.wl + nn * 256 + (koff ^ ((nn & 7) << 4)));
      acc[cc] = __builtin_amdgcn_mfma_f32_16x16x32_bf16(af[kt], bfr, acc[cc], 0, 0, 0);
    }
  }
  __syncthreads();  // wl free -> out
#pragma unroll
  for (int cc = 0; cc < 8; ++cc) {          // write via perm: natural row order
    uB.out[pr0 * D + cc * 16 + lm] = acc[cc][0];
    uB.out[pr1 * D + cc * 16 + lm] = acc[cc][1];
    uB.out[pr2 * D + cc * 16 + lm] = acc[cc][2];
    uB.out[pr3 * D + cc * 16 + lm] = acc[cc][3];
  }
  __syncthreads();
  int tc = tx & 31, tr = tx >> 5;
  f32x4 s = {0.f, 0.f, 0.f, 0.f}, q = {0.f, 0.f, 0.f, 0.f};
#pragma unroll
  for (int i = 0; i < 8; ++i) {
    int rr = i * 8 + tr;
    f32x4 v = *(f32x4*)&uB.out[rr * D + tc * 4];
    u16x4 o; o[0] = f2bf(v[0]); o[1] = f2bf(v[1]); o[2] = f2bf(v[2]); o[3] = f2bf(v[3]);
    *(u16x4*)(t + (size_t)(r0 + rr) * D + tc * 4) = o;
    if (r0 + rr < N) { s += v; q += v * v; }
  }
  *(f32x4*)&red[tr * D + tc * 4] = s;
  *(f32x4*)&red[8 * D + tr * D + tc * 4] = q;
  __syncthreads();
  int colx = tx & 127, which = tx >> 7;
  float S = 0.f;
#pragma unroll
  for (int jj = 0; jj < 8; ++jj) S += red[which * 8 * D + jj * D + colx];
  partials[(size_t)blockIdx.x * 256 + tx] = S;
}

// reduce stage 1: 64 blocks -> partial2[64][256]
__global__ __launch_bounds__(256) void k_red1(const float* __restrict__ partials, int NB,
                                              float* __restrict__ partial2) {
  int tx = threadIdx.x;
  float S = 0.f;
  for (int b = blockIdx.x; b < NB; b += 64) S += partials[(size_t)b * 256 + tx];
  partial2[(size_t)blockIdx.x * 256 + tx] = S;
}

// ---------------- GEMM2 core: in-block BN finalize + register-direct A + DMA W ----------------
__device__ __forceinline__ void gemm2_core(const unsigned short* t,
                                           const unsigned short* wt,
                                           const float* bias,
                                           const float* partial2,
                                           const float* gamma, const float* beta, int N,
                                           unsigned short* wl, float* statssh,
                                           float* outbuf, int r0) {
  int tx = threadIdx.x;
  stage_w_dma(wt, wl, tx);       // async DMA
  int l = tx & 63, w = tx >> 6;
  int lm = l & 15, lg = l >> 4;
  int row = 16 * w + lm;
  const u16x8* tg8 = (const u16x8*)(t + (size_t)(r0 + row) * D);
  u16x8 tv[4];                    // hoist t loads (overlap with stats reduce)
#pragma unroll
  for (int kt = 0; kt < 4; ++kt) tv[kt] = tg8[kt * 4 + lg];
  // in-block BN finalize from partial2 (identical fp32 order as old k_finalize)
  float S = 0.f;
#pragma unroll 8
  for (int b = 0; b < 64; ++b) S += partial2[(size_t)b * 256 + tx];
  statssh[tx] = S;
  __syncthreads();                // statssh sums ready; also drains W DMA
  if (tx < D) {
    float mu = statssh[tx] / (float)N;
    float var = statssh[D + tx] / (float)N - mu * mu;
    float rstd = rsqrtf(fmaxf(var, 0.f) + BN_EPS);
    float A = gamma[tx] * rstd;
    statssh[tx] = A;
    statssh[D + tx] = beta[tx] - mu * A;
  }
  __syncthreads();
  bf16x8 af[4];
#pragma unroll
  for (int kt = 0; kt < 4; ++kt) {
    u16x8 v = tv[kt];
    int c0 = (kt * 4 + lg) * 8;
    f32x4 a0 = *(const f32x4*)&statssh[c0];
    f32x4 a1 = *(const f32x4*)&statssh[c0 + 4];
    f32x4 b0 = *(const f32x4*)&statssh[D + c0];
    f32x4 b1v = *(const f32x4*)&statssh[D + c0 + 4];
    u16x8 o;
    o[0] = f2bf(fmaxf(bf2f(v[0]) * a0[0] + b0[0], 0.f));
    o[1] = f2bf(fmaxf(bf2f(v[1]) * a0[1] + b0[1], 0.f));
    o[2] = f2bf(fmaxf(bf2f(v[2]) * a0[2] + b0[2], 0.f));
    o[3] = f2bf(fmaxf(bf2f(v[3]) * a0[3] + b0[3], 0.f));
    o[4] = f2bf(fmaxf(bf2f(v[4]) * a1[0] + b1v[0], 0.f));
    o[5] = f2bf(fmaxf(bf2f(v[5]) * a1[1] + b1v[1], 0.f));
    o[6] = f2bf(fmaxf(bf2f(v[6]) * a1[2] + b1v[2], 0.f));
    o[7] = f2bf(fmaxf(bf2f(v[7]) * a1[3] + b1v[3], 0.f));
    af[kt] = *(bf16x8*)&o;
  }
  f32x4 acc[8];
#pragma unroll
  for (int c = 0; c < 8; ++c) { float bv = bias[c * 16 + lm]; acc[c] = (f32x4){bv, bv, bv, bv}; }
#pragma unroll
  for (int kt = 0; kt < 4; ++kt) {
    int koff = kt * 64 + lg * 16;
#pragma unroll
    for (int c = 0; c < 8; ++c) {
      int nn = c * 16 + lm;
      bf16x8 bfr = *(const bf16x8*)((const char*)wl + nn * 256 + (koff ^ ((nn & 7) << 4)));
      acc[c] = __builtin_amdgcn_mfma_f32_16x16x32_bf16(af[kt], bfr, acc[c], 0, 0, 0);
    }
  }
  __syncthreads();  // wl free -> out
#pragma unroll
  for (int c = 0; c < 8; ++c)
#pragma unroll
    for (int r = 0; r < 4; ++r)
      outbuf[(16 * w + 4 * lg + r) * D + c * 16 + lm] = acc[c][r];
  __syncthreads();
}

// layers 0..2: h_l = relu(bn(t)) @ W2 + b2 (bf16, write-only)
__global__ __launch_bounds__(256) void k_gemm2(const unsigned short* __restrict__ t,
                                               const unsigned short* __restrict__ wt,
                                               const float* __restrict__ bias,
                                               const float* __restrict__ partial2,
                                               const float* __restrict__ gamma,
                                               const float* __restrict__ beta,
                                               unsigned short* __restrict__ h, int N) {
  __shared__ union { unsigned short wl[D * D]; float out[64 * D]; } uB;
  __shared__ float statssh[2 * D];
  int tx = threadIdx.x;
  int r0 = blockIdx.x * 64;
  gemm2_core(t, wt, bias, partial2, gamma, beta, N, uB.wl, statssh, uB.out, r0);
  int tc = tx & 31, tr = tx >> 5;
#pragma unroll
  for (int i = 0; i < 8; ++i) {
    int row = i * 8 + tr;
    int gr = r0 + row;
    if (gr < N) {
      f32x4 v = *(f32x4*)&uB.out[row * D + tc * 4];
      u16x4 hb; hb[0] = f2bf(v[0]); hb[1] = f2bf(v[1]); hb[2] = f2bf(v[2]); hb[3] = f2bf(v[3]);
      *(u16x4*)(h + (size_t)gr * D + tc * 4) = hb;
    }
  }
}

// layer 3: node_pool = h0+h1+h2+h3 (h3 in-register fp32, never stored)
__global__ __launch_bounds__(256) void k_gemm2_last(const unsigned short* __restrict__ t,
                                                    const unsigned short* __restrict__ wt,
                                                    const float* __restrict__ bias,
                                                    const float* __restrict__ partial2,
                                                    const float* __restrict__ gamma,
                                                    const float* __restrict__ beta,
                                                    const unsigned short* __restrict__ h0,
                                                    const unsigned short* __restrict__ h1,
                                                    const unsigned short* __restrict__ h2,
                                                    float* __restrict__ np, int N) {
  __shared__ union { unsigned short wl[D * D]; float out[64 * D]; } uB;
  __shared__ float statssh[2 * D];
  int tx = threadIdx.x;
  int r0 = blockIdx.x * 64;
  gemm2_core(t, wt, bias, partial2, gamma, beta, N, uB.wl, statssh, uB.out, r0);
  int tc = tx & 31, tr = tx >> 5;
#pragma unroll
  for (int i = 0; i < 8; ++i) {
    int row = i * 8 + tr;
    int gr = r0 + row;
    if (gr < N) {
      f32x4 v = *(f32x4*)&uB.out[row * D + tc * 4];
      size_t o4 = (size_t)gr * D + tc * 4;
      u16x4 a = *(const u16x4*)(h0 + o4);
      u16x4 b = *(const u16x4*)(h1 + o4);
      u16x4 cc = *(const u16x4*)(h2 + o4);
      f32x4 o;
#pragma unroll
      for (int k = 0; k < 4; ++k)
        o[k] = v[k] + (bf2f(a[k]) + bf2f(b[k])) + bf2f(cc[k]);
      *(f32x4*)(np + o4) = o;
    }
  }
}

// ---------------- pooling ----------------
__global__ __launch_bounds__(256) void k_gpool(const float* __restrict__ np,
                                               const int* __restrict__ bound,
                                               float* __restrict__ gp) {
  __shared__ float red[8 * D];
  int g = blockIdx.x;
  int s = bound[g], e = bound[g + 1];
  int tc = threadIdx.x & 31, tr = threadIdx.x >> 5;
  f32x4 a = {0.f, 0.f, 0.f, 0.f};
  for (int r = s + tr; r < e; r += 8)
    a += *(const f32x4*)(np + (size_t)r * D + tc * 4);
  *(f32x4*)&red[tr * D + tc * 4] = a;
  __syncthreads();
  if (threadIdx.x < D) {
    float v = 0.f;
#pragma unroll
    for (int j = 0; j < 8; ++j) v += red[j * D + threadIdx.x];
    float c = (float)(e - s);
    gp[(size_t)g * D + threadIdx.x] = v / fmaxf(c, 1.f);
  }
}

// ---------------- launch ----------------
extern "C" void kernel_launch(void* const* d_in, const int* in_sizes, int n_in,
                              void* d_out, int out_size, void* d_ws,
                              size_t ws_size, hipStream_t stream) {
  const float* x = (const float*)d_in[0];
  const int* ei = (const int*)d_in[1];
  const int* batch = (const int*)d_in[2];
  const float* W1 = (const float*)d_in[3];
  const float* b1 = (const float*)d_in[4];
  const float* gamma = (const float*)d_in[5];
  const float* beta = (const float*)d_in[6];
  const float* W2 = (const float*)d_in[7];
  const float* b2 = (const float*)d_in[8];
  int N = in_sizes[0] / D;
  int E = in_sizes[1] / 2;
  int Npad = (N + 63) & ~63;
  int gb = Npad / 64;
  int B = (E + EPB - 1) / EPB;
  int nbin = (N + 255) / 256;
  int M = nbin * B;

  float* out = (float*)d_out;
  float* node_pool = out;
  float* g_pool = out + (size_t)N * D;

  char* wp = (char*)d_ws;
  unsigned short* hx = (unsigned short*)wp;   wp += (size_t)Npad * D * 2;
  unsigned short* t = (unsigned short*)wp;    wp += (size_t)Npad * D * 2;
  unsigned short* hbuf[3];
  for (int l = 0; l < 3; ++l) { hbuf[l] = (unsigned short*)wp; wp += (size_t)Npad * D * 2; }
  unsigned short* wt = (unsigned short*)wp;   wp += (size_t)8 * D * D * 2;
  float* partials = (float*)wp;               wp += (size_t)gb * 256 * 4;
  float* partial2 = (float*)wp;               wp += (size_t)64 * 256 * 4;
  int* bound = (int*)wp;                      wp += (size_t)(GNUM + 4) * 4;
  int* rowptr = (int*)wp;                     wp += (size_t)(N + 1) * 4;
  int* perm = (int*)wp;                       wp += (size_t)Npad * 4;
  int* hist = (int*)wp;                       wp += (size_t)SH_MAX * 4;
  int* off = (int*)wp;                        wp += (size_t)SH_MAX * 4;
  int* col = (int*)wp;                        wp += (size_t)E * 4;
  int2* sorted = (int2*)wp;                   wp += (size_t)E * 8;

  int xblocks = (N * 32 + 255) / 256;
  k_prep<<<8 + xblocks, 256, 0, stream>>>(W1, W2, wt, x, hx, N * 32);
  k_hist<<<B, 256, 0, stream>>>(ei, E, B, nbin, hist);
  k_hscan<<<1, 1024, 0, stream>>>(hist, M, off, rowptr, N, E);
  k_scatter<<<B, 256, 0, stream>>>(ei, E, B, nbin, off, sorted);
  k_build<<<nbin, 256, 0, stream>>>(sorted, off, B, nbin, E, N, rowptr, col);
  k_perm<<<gb, 64, 0, stream>>>(rowptr, N, perm, batch, bound);

  for (int ll = 0; ll < LNUM; ++ll) {
    const unsigned short* hin = (ll == 0) ? hx : hbuf[ll - 1];
    k_layer1<<<gb, 256, 0, stream>>>(hin, rowptr, col, perm, wt + (size_t)ll * D * D,
                                     b1 + (size_t)ll * D, t, partials, N);
    k_red1<<<64, 256, 0, stream>>>(partials, gb, partial2);
    if (ll < LNUM - 1) {
      k_gemm2<<<gb, 256, 0, stream>>>(t, wt + (size_t)(LNUM + ll) * D * D,
                                      b2 + (size_t)ll * D, partial2,
                                      gamma + (size_t)ll * D, beta + (size_t)ll * D,
                                      hbuf[ll], N);
    } else {
      k_gemm2_last<<<gb, 256, 0, stream>>>(t, wt + (size_t)(LNUM + ll) * D * D,
                                           b2 + (size_t)ll * D, partial2,
                                           gamma + (size_t)ll * D, beta + (size_t)ll * D,
                                           hbuf[0], hbuf[1], hbuf[2], node_pool, N);
    }
  }
  k_gpool<<<GNUM, 256, 0, stream>>>(node_pool, bound, g_pool);
}

// Round 16
// 379.470 us; speedup vs baseline: 1.0765x; 1.0041x over previous
//
#include <hip/hip_runtime.h>

#define D 128
#define GNUM 64
#define LNUM 4
#define BN_EPS 1e-5f
#define EPB 16384          // edges per hist/scatter block
#define SH_MAX 12544       // max NBIN*B the one-block scan supports

typedef short bf16x8 __attribute__((ext_vector_type(8)));       // 8 bf16 = 4 VGPR
typedef float f32x4 __attribute__((ext_vector_type(4)));
typedef unsigned short u16x8 __attribute__((ext_vector_type(8)));
typedef unsigned short u16x4 __attribute__((ext_vector_type(4)));

__device__ __forceinline__ float bf2f(unsigned short u) {
  union { unsigned int i; float f; } v; v.i = ((unsigned int)u) << 16; return v.f;
}
__device__ __forceinline__ unsigned short f2bf(float f) {
  union { float f; unsigned int i; } v; v.f = f;
  unsigned int b = v.i;
  return (unsigned short)((b + 0x7FFFu + ((b >> 16) & 1u)) >> 16);
}

// Stage one 32KB pre-swizzled W tile: direct global->LDS DMA.
__device__ __forceinline__ void stage_w_dma(const unsigned short* wsw,
                                            unsigned short* wl, int tx) {
  int wv = tx >> 6, ln = tx & 63;
#pragma unroll
  for (int i = 0; i < 8; ++i) {
    int base_chunk = wv * 64 + i * 256;   // wave-uniform u16x8 index
    __builtin_amdgcn_global_load_lds(
        (const __attribute__((address_space(1))) unsigned int*)(wsw + (size_t)(base_chunk + ln) * 8),
        (__attribute__((address_space(3))) unsigned int*)(wl + (size_t)base_chunk * 8),
        16, 0, 0);
  }
}

// ---------------- CSR build: atomic-free binned counting sort ----------------
__global__ __launch_bounds__(256) void k_hist(const int* __restrict__ ei, int E,
                                              int B, int nbin, int* __restrict__ hist) {
  __shared__ int lh[256];
  int b = blockIdx.x, tx = threadIdx.x;
  lh[tx] = 0;
  __syncthreads();
  int s = b * EPB, e = min(s + EPB, E);
  for (int j = s + tx; j < e; j += 256) atomicAdd(&lh[ei[(size_t)E + j] >> 8], 1);
  __syncthreads();
  if (tx < nbin) hist[tx * B + b] = lh[tx];
}

__global__ __launch_bounds__(1024) void k_hscan(const int* __restrict__ hist, int M,
                                                int* __restrict__ off,
                                                int* __restrict__ rowptr, int N, int E) {
  __shared__ int sh[SH_MAX];
  __shared__ int sh2[1024];
  int tx = threadIdx.x;
  int chunk = (M + 1023) / 1024;
  for (int i = 0; i < chunk; ++i) {
    int idx = tx * chunk + i;
    sh[idx] = (idx < M) ? hist[idx] : 0;
  }
  __syncthreads();
  int s = 0;
  for (int i = 0; i < chunk; ++i) s += sh[tx * chunk + i];
  sh2[tx] = s;
  __syncthreads();
  for (int o = 1; o < 1024; o <<= 1) {
    int u = (tx >= o) ? sh2[tx - o] : 0;
    __syncthreads();
    sh2[tx] += u;
    __syncthreads();
  }
  int run = (tx == 0) ? 0 : sh2[tx - 1];
  for (int i = 0; i < chunk; ++i) {
    int idx = tx * chunk + i;
    if (idx < M) { int v = sh[idx]; off[idx] = run; run += v; }
  }
  if (tx == 0) rowptr[N] = E;
}

// scatter packed (src<<8 | dst&255): halves write traffic vs int2
__global__ __launch_bounds__(256) void k_scatter(const int* __restrict__ ei, int E,
                                                 int B, int nbin,
                                                 const int* __restrict__ off,
                                                 int* __restrict__ sorted) {
  __shared__ int cur[256];
  int b = blockIdx.x, tx = threadIdx.x;
  if (tx < nbin) cur[tx] = off[tx * B + b];
  __syncthreads();
  int s = b * EPB, e = min(s + EPB, E);
  for (int j = s + tx; j < e; j += 256) {
    int d = ei[(size_t)E + j];
    int sc = ei[j];
    int p = atomicAdd(&cur[d >> 8], 1);
    sorted[p] = (sc << 8) | (d & 255);
  }
}

__global__ __launch_bounds__(256) void k_build(const int* __restrict__ sorted,
                                               const int* __restrict__ off,
                                               int B, int nbin, int E, int N,
                                               int* __restrict__ rowptr,
                                               int* __restrict__ col) {
  __shared__ int cnt[256], excl[256], cur[256];
  int beta = blockIdx.x, tx = threadIdx.x;
  int s = off[beta * B];
  int e = (beta + 1 < nbin) ? off[(beta + 1) * B] : E;
  cnt[tx] = 0;
  __syncthreads();
  for (int j = s + tx; j < e; j += 256) atomicAdd(&cnt[sorted[j] & 255], 1);
  __syncthreads();
  int v = cnt[tx];
  excl[tx] = v;
  __syncthreads();
  for (int o = 1; o < 256; o <<= 1) {
    int u = (tx >= o) ? excl[tx - o] : 0;
    __syncthreads();
    excl[tx] += u;
    __syncthreads();
  }
  int ex = excl[tx] - v;
  int n = beta * 256 + tx;
  if (n < N) rowptr[n] = s + ex;
  cur[tx] = s + ex;
  __syncthreads();
  for (int j = s + tx; j < e; j += 256) {
    int p = sorted[j];
    int q = atomicAdd(&cur[p & 255], 1);
    col[q] = ((unsigned int)p) >> 8;
  }
}

// per-64-tile degree rank (+ block 0 computes graph bounds)
__global__ __launch_bounds__(64) void k_perm(const int* __restrict__ rowptr, int N,
                                             int* __restrict__ perm,
                                             const int* __restrict__ batch,
                                             int* __restrict__ bound) {
  __shared__ int degs[64];
  int r0 = blockIdx.x * 64;
  int i = threadIdx.x;
  int n = r0 + i;
  int d = (n < N) ? (rowptr[n + 1] - rowptr[n]) : -1;
  degs[i] = d;
  if (blockIdx.x == 0) {
    for (int g = i; g <= GNUM; g += 64) {
      int lo = 0, hi = N;
      while (lo < hi) { int mid = (lo + hi) >> 1; if (batch[mid] < g) lo = mid + 1; else hi = mid; }
      bound[g] = lo;
    }
  }
  __syncthreads();
  int rank = 0;
#pragma unroll
  for (int j = 0; j < 64; ++j) {
    int dj = degs[j];
    if (dj < d || (dj == d && j < i)) ++rank;
  }
  perm[r0 + rank] = i;
}

// ---------------- prep: W (blocks 0..7) + x (remaining blocks) ----------------
__global__ __launch_bounds__(256) void k_prep(const float* __restrict__ W1,
                                              const float* __restrict__ W2,
                                              unsigned short* __restrict__ wt,
                                              const float* __restrict__ x,
                                              unsigned short* __restrict__ hx, int total4) {
  if (blockIdx.x < 8) {
    int l = blockIdx.x;
    const float* W = (l < LNUM) ? (W1 + (size_t)l * D * D) : (W2 + (size_t)(l - LNUM) * D * D);
    unsigned short* o = wt + (size_t)l * D * D;
#pragma unroll
    for (int i = 0; i < 64; ++i) {
      int idx = threadIdx.x + 256 * i;       // idx = k*128 + n
      int k = idx >> 7, n = idx & 127;
      int kd = (((k >> 3) ^ (n & 7)) << 3) | (k & 7);   // pre-swizzled LDS image
      o[n * D + kd] = f2bf(W[idx]);
    }
  } else {
    int i = (blockIdx.x - 8) * 256 + threadIdx.x;
    if (i < total4) {
      f32x4 v = ((const f32x4*)x)[i];
      u16x4 o; o[0] = f2bf(v[0]); o[1] = f2bf(v[1]); o[2] = f2bf(v[2]); o[3] = f2bf(v[3]);
      ((u16x4*)hx)[i] = o;
    }
  }
}

// ---------------- fused layer-1 (reg-direct gather, degree-sorted slots, DMA W) ----------------
__global__ __launch_bounds__(256, 3) void k_layer1(const unsigned short* __restrict__ hin,
                                                const int* __restrict__ rowptr,
                                                const int* __restrict__ col,
                                                const int* __restrict__ perm,
                                                const unsigned short* __restrict__ wt,
                                                const float* __restrict__ bias,
                                                unsigned short* __restrict__ t,
                                                float* __restrict__ partials, int N) {
  __shared__ union { unsigned short wl[D * D]; float out[64 * D]; } uB;  // 32KB
  __shared__ float red[2 * 8 * D];                                      // 8KB
  int tx = threadIdx.x;
  int r0 = blockIdx.x * 64;
  stage_w_dma(wt, uB.wl, tx);    // async DMA; __syncthreads below drains it
  int l = tx & 63, w = tx >> 6;
  int lm = l & 15, lg = l >> 4;
  int lr = perm[r0 + 16 * w + lm];
  int pr0 = perm[r0 + 16 * w + 4 * lg + 0];
  int pr1 = perm[r0 + 16 * w + 4 * lg + 1];
  int pr2 = perm[r0 + 16 * w + 4 * lg + 2];
  int pr3 = perm[r0 + 16 * w + 4 * lg + 3];
  int n = r0 + lr;
  const u16x8* h8 = (const u16x8*)hin;
  f32x4 sA[4] = {{0.f,0.f,0.f,0.f},{0.f,0.f,0.f,0.f},{0.f,0.f,0.f,0.f},{0.f,0.f,0.f,0.f}};
  f32x4 sB[4] = {{0.f,0.f,0.f,0.f},{0.f,0.f,0.f,0.f},{0.f,0.f,0.f,0.f},{0.f,0.f,0.f,0.f}};
  int e0 = 0, e1 = 0;
  if (n < N) { e0 = rowptr[n]; e1 = rowptr[n + 1]; }
  int j = e0;
  for (; j + 3 < e1; j += 4) {               // 16 x 16B loads in flight
    size_t a0i = (size_t)col[j] * 16 + lg;
    size_t a1i = (size_t)col[j + 1] * 16 + lg;
    size_t a2i = (size_t)col[j + 2] * 16 + lg;
    size_t a3i = (size_t)col[j + 3] * 16 + lg;
    u16x8 u00 = h8[a0i], u01 = h8[a0i + 4], u02 = h8[a0i + 8], u03 = h8[a0i + 12];
    u16x8 u10 = h8[a1i], u11 = h8[a1i + 4], u12 = h8[a1i + 8], u13 = h8[a1i + 12];
    u16x8 u20 = h8[a2i], u21 = h8[a2i + 4], u22 = h8[a2i + 8], u23 = h8[a2i + 12];
    u16x8 u30 = h8[a3i], u31 = h8[a3i + 4], u32 = h8[a3i + 8], u33 = h8[a3i + 12];
#pragma unroll
    for (int k = 0; k < 4; ++k) {
      sA[0][k] += (bf2f(u00[k]) + bf2f(u10[k])) + (bf2f(u20[k]) + bf2f(u30[k]));
      sB[0][k] += (bf2f(u00[4+k]) + bf2f(u10[4+k])) + (bf2f(u20[4+k]) + bf2f(u30[4+k]));
      sA[1][k] += (bf2f(u01[k]) + bf2f(u11[k])) + (bf2f(u21[k]) + bf2f(u31[k]));
      sB[1][k] += (bf2f(u01[4+k]) + bf2f(u11[4+k])) + (bf2f(u21[4+k]) + bf2f(u31[4+k]));
      sA[2][k] += (bf2f(u02[k]) + bf2f(u12[k])) + (bf2f(u22[k]) + bf2f(u32[k]));
      sB[2][k] += (bf2f(u02[4+k]) + bf2f(u12[4+k])) + (bf2f(u22[4+k]) + bf2f(u32[4+k]));
      sA[3][k] += (bf2f(u03[k]) + bf2f(u13[k])) + (bf2f(u23[k]) + bf2f(u33[k]));
      sB[3][k] += (bf2f(u03[4+k]) + bf2f(u13[4+k])) + (bf2f(u23[4+k]) + bf2f(u33[4+k]));
    }
  }
  for (; j < e1; ++j) {
    size_t a0i = (size_t)col[j] * 16 + lg;
    u16x8 u00 = h8[a0i], u01 = h8[a0i + 4], u02 = h8[a0i + 8], u03 = h8[a0i + 12];
#pragma unroll
    for (int k = 0; k < 4; ++k) {
      sA[0][k] += bf2f(u00[k]);  sB[0][k] += bf2f(u00[4+k]);
      sA[1][k] += bf2f(u01[k]);  sB[1][k] += bf2f(u01[4+k]);
      sA[2][k] += bf2f(u02[k]);  sB[2][k] += bf2f(u02[4+k]);
      sA[3][k] += bf2f(u03[k]);  sB[3][k] += bf2f(u03[4+k]);
    }
  }
  bf16x8 af[4];
  if (n < N) {
    float inv = (e1 > e0) ? 1.f / (float)(e1 - e0) : 0.f;
#pragma unroll
    for (int kt = 0; kt < 4; ++kt) {
      u16x8 hv = h8[(size_t)n * 16 + kt * 4 + lg];
      u16x8 o;
#pragma unroll
      for (int k = 0; k < 4; ++k) {
        o[k] = f2bf(bf2f(hv[k]) + sA[kt][k] * inv);
        o[4 + k] = f2bf(bf2f(hv[4 + k]) + sB[kt][k] * inv);
      }
      af[kt] = *(bf16x8*)&o;
    }
  } else {
#pragma unroll
    for (int kt = 0; kt < 4; ++kt) af[kt] = (bf16x8){0,0,0,0,0,0,0,0};
  }
  __syncthreads();   // drains DMA (vmcnt) + all lanes ready
  f32x4 acc[8];
#pragma unroll
  for (int cc = 0; cc < 8; ++cc) { float bv = bias[cc * 16 + lm]; acc[cc] = (f32x4){bv, bv, bv, bv}; }
#pragma unroll
  for (int kt = 0; kt < 4; ++kt) {
    int koff = kt * 64 + lg * 16;
#pragma unroll
    for (int cc = 0; cc < 8; ++cc) {
      int nn = cc * 16 + lm;
      bf16x8 bfr = *(const bf16x8*)((const char*)uB.wl + nn * 256 + (koff ^ ((nn & 7) << 4)));
      acc[cc] = __builtin_amdgcn_mfma_f32_16x16x32_bf16(af[kt], bfr, acc[cc], 0, 0, 0);
    }
  }
  __syncthreads();  // wl free -> out
#pragma unroll
  for (int cc = 0; cc < 8; ++cc) {          // write via perm: natural row order
    uB.out[pr0 * D + cc * 16 + lm] = acc[cc][0];
    uB.out[pr1 * D + cc * 16 + lm] = acc[cc][1];
    uB.out[pr2 * D + cc * 16 + lm] = acc[cc][2];
    uB.out[pr3 * D + cc * 16 + lm] = acc[cc][3];
  }
  __syncthreads();
  int tc = tx & 31, tr = tx >> 5;
  f32x4 s = {0.f, 0.f, 0.f, 0.f}, q = {0.f, 0.f, 0.f, 0.f};
#pragma unroll
  for (int i = 0; i < 8; ++i) {
    int rr = i * 8 + tr;
    f32x4 v = *(f32x4*)&uB.out[rr * D + tc * 4];
    u16x4 o; o[0] = f2bf(v[0]); o[1] = f2bf(v[1]); o[2] = f2bf(v[2]); o[3] = f2bf(v[3]);
    *(u16x4*)(t + (size_t)(r0 + rr) * D + tc * 4) = o;
    if (r0 + rr < N) { s += v; q += v * v; }
  }
  *(f32x4*)&red[tr * D + tc * 4] = s;
  *(f32x4*)&red[8 * D + tr * D + tc * 4] = q;
  __syncthreads();
  int colx = tx & 127, which = tx >> 7;
  float S = 0.f;
#pragma unroll
  for (int jj = 0; jj < 8; ++jj) S += red[which * 8 * D + jj * D + colx];
  partials[(size_t)blockIdx.x * 256 + tx] = S;
}

// reduce stage 1: 64 blocks -> partial2[64][256]
__global__ __launch_bounds__(256) void k_red1(const float* __restrict__ partials, int NB,
                                              float* __restrict__ partial2) {
  int tx = threadIdx.x;
  float S = 0.f;
  for (int b = blockIdx.x; b < NB; b += 64) S += partials[(size_t)b * 256 + tx];
  partial2[(size_t)blockIdx.x * 256 + tx] = S;
}

// ---------------- GEMM2 core: in-block BN finalize (single barrier) + reg-direct A + DMA W ----------------
__device__ __forceinline__ void gemm2_core(const unsigned short* t,
                                           const unsigned short* wt,
                                           const float* bias,
                                           const float* partial2,
                                           const float* gamma, const float* beta, int N,
                                           unsigned short* wl, float* statssh,
                                           float* outbuf, int r0) {
  int tx = threadIdx.x;
  stage_w_dma(wt, wl, tx);       // async DMA
  int l = tx & 63, w = tx >> 6;
  int lm = l & 15, lg = l >> 4;
  int row = 16 * w + lm;
  const u16x8* tg8 = (const u16x8*)(t + (size_t)(r0 + row) * D);
  u16x8 tv[4];                    // hoist t loads (overlap with stats reduce)
#pragma unroll
  for (int kt = 0; kt < 4; ++kt) tv[kt] = tg8[kt * 4 + lg];
  // in-block BN finalize: threads 0..127 reduce BOTH their S and Q columns
  // (same serial order per column as before -> bit-identical stats)
  if (tx < D) {
    float S = 0.f, Q = 0.f;
#pragma unroll 8
    for (int b = 0; b < 64; ++b) {
      S += partial2[(size_t)b * 256 + tx];
      Q += partial2[(size_t)b * 256 + 128 + tx];
    }
    float mu = S / (float)N;
    float var = Q / (float)N - mu * mu;
    float rstd = rsqrtf(fmaxf(var, 0.f) + BN_EPS);
    float A = gamma[tx] * rstd;
    statssh[tx] = A;
    statssh[D + tx] = beta[tx] - mu * A;
  }
  __syncthreads();                // stats ready; also drains W DMA
  bf16x8 af[4];
#pragma unroll
  for (int kt = 0; kt < 4; ++kt) {
    u16x8 v = tv[kt];
    int c0 = (kt * 4 + lg) * 8;
    f32x4 a0 = *(const f32x4*)&statssh[c0];
    f32x4 a1 = *(const f32x4*)&statssh[c0 + 4];
    f32x4 b0 = *(const f32x4*)&statssh[D + c0];
    f32x4 b1v = *(const f32x4*)&statssh[D + c0 + 4];
    u16x8 o;
    o[0] = f2bf(fmaxf(bf2f(v[0]) * a0[0] + b0[0], 0.f));
    o[1] = f2bf(fmaxf(bf2f(v[1]) * a0[1] + b0[1], 0.f));
    o[2] = f2bf(fmaxf(bf2f(v[2]) * a0[2] + b0[2], 0.f));
    o[3] = f2bf(fmaxf(bf2f(v[3]) * a0[3] + b0[3], 0.f));
    o[4] = f2bf(fmaxf(bf2f(v[4]) * a1[0] + b1v[0], 0.f));
    o[5] = f2bf(fmaxf(bf2f(v[5]) * a1[1] + b1v[1], 0.f));
    o[6] = f2bf(fmaxf(bf2f(v[6]) * a1[2] + b1v[2], 0.f));
    o[7] = f2bf(fmaxf(bf2f(v[7]) * a1[3] + b1v[3], 0.f));
    af[kt] = *(bf16x8*)&o;
  }
  f32x4 acc[8];
#pragma unroll
  for (int c = 0; c < 8; ++c) { float bv = bias[c * 16 + lm]; acc[c] = (f32x4){bv, bv, bv, bv}; }
#pragma unroll
  for (int kt = 0; kt < 4; ++kt) {
    int koff = kt * 64 + lg * 16;
#pragma unroll
    for (int c = 0; c < 8; ++c) {
      int nn = c * 16 + lm;
      bf16x8 bfr = *(const bf16x8*)((const char*)wl + nn * 256 + (koff ^ ((nn & 7) << 4)));
      acc[c] = __builtin_amdgcn_mfma_f32_16x16x32_bf16(af[kt], bfr, acc[c], 0, 0, 0);
    }
  }
  __syncthreads();  // wl free -> out
#pragma unroll
  for (int c = 0; c < 8; ++c)
#pragma unroll
    for (int r = 0; r < 4; ++r)
      outbuf[(16 * w + 4 * lg + r) * D + c * 16 + lm] = acc[c][r];
  __syncthreads();
}

// layers 0..2: h_l = relu(bn(t)) @ W2 + b2 (bf16, write-only)
__global__ __launch_bounds__(256) void k_gemm2(const unsigned short* __restrict__ t,
                                               const unsigned short* __restrict__ wt,
                                               const float* __restrict__ bias,
                                               const float* __restrict__ partial2,
                                               const float* __restrict__ gamma,
                                               const float* __restrict__ beta,
                                               unsigned short* __restrict__ h, int N) {
  __shared__ union { unsigned short wl[D * D]; float out[64 * D]; } uB;
  __shared__ float statssh[2 * D];
  int tx = threadIdx.x;
  int r0 = blockIdx.x * 64;
  gemm2_core(t, wt, bias, partial2, gamma, beta, N, uB.wl, statssh, uB.out, r0);
  int tc = tx & 31, tr = tx >> 5;
#pragma unroll
  for (int i = 0; i < 8; ++i) {
    int row = i * 8 + tr;
    int gr = r0 + row;
    if (gr < N) {
      f32x4 v = *(f32x4*)&uB.out[row * D + tc * 4];
      u16x4 hb; hb[0] = f2bf(v[0]); hb[1] = f2bf(v[1]); hb[2] = f2bf(v[2]); hb[3] = f2bf(v[3]);
      *(u16x4*)(h + (size_t)gr * D + tc * 4) = hb;
    }
  }
}

// layer 3: node_pool = h0+h1+h2+h3 (h3 in-register fp32, never stored)
__global__ __launch_bounds__(256) void k_gemm2_last(const unsigned short* __restrict__ t,
                                                    const unsigned short* __restrict__ wt,
                                                    const float* __restrict__ bias,
                                                    const float* __restrict__ partial2,
                                                    const float* __restrict__ gamma,
                                                    const float* __restrict__ beta,
                                                    const unsigned short* __restrict__ h0,
                                                    const unsigned short* __restrict__ h1,
                                                    const unsigned short* __restrict__ h2,
                                                    float* __restrict__ np, int N) {
  __shared__ union { unsigned short wl[D * D]; float out[64 * D]; } uB;
  __shared__ float statssh[2 * D];
  int tx = threadIdx.x;
  int r0 = blockIdx.x * 64;
  gemm2_core(t, wt, bias, partial2, gamma, beta, N, uB.wl, statssh, uB.out, r0);
  int tc = tx & 31, tr = tx >> 5;
#pragma unroll
  for (int i = 0; i < 8; ++i) {
    int row = i * 8 + tr;
    int gr = r0 + row;
    if (gr < N) {
      f32x4 v = *(f32x4*)&uB.out[row * D + tc * 4];
      size_t o4 = (size_t)gr * D + tc * 4;
      u16x4 a = *(const u16x4*)(h0 + o4);
      u16x4 b = *(const u16x4*)(h1 + o4);
      u16x4 cc = *(const u16x4*)(h2 + o4);
      f32x4 o;
#pragma unroll
      for (int k = 0; k < 4; ++k)
        o[k] = v[k] + (bf2f(a[k]) + bf2f(b[k])) + bf2f(cc[k]);
      *(f32x4*)(np + o4) = o;
    }
  }
}

// ---------------- pooling ----------------
__global__ __launch_bounds__(256) void k_gpool(const float* __restrict__ np,
                                               const int* __restrict__ bound,
                                               float* __restrict__ gp) {
  __shared__ float red[8 * D];
  int g = blockIdx.x;
  int s = bound[g], e = bound[g + 1];
  int tc = threadIdx.x & 31, tr = threadIdx.x >> 5;
  f32x4 a = {0.f, 0.f, 0.f, 0.f};
  for (int r = s + tr; r < e; r += 8)
    a += *(const f32x4*)(np + (size_t)r * D + tc * 4);
  *(f32x4*)&red[tr * D + tc * 4] = a;
  __syncthreads();
  if (threadIdx.x < D) {
    float v = 0.f;
#pragma unroll
    for (int j = 0; j < 8; ++j) v += red[j * D + threadIdx.x];
    float c = (float)(e - s);
    gp[(size_t)g * D + threadIdx.x] = v / fmaxf(c, 1.f);
  }
}

// ---------------- launch ----------------
extern "C" void kernel_launch(void* const* d_in, const int* in_sizes, int n_in,
                              void* d_out, int out_size, void* d_ws,
                              size_t ws_size, hipStream_t stream) {
  const float* x = (const float*)d_in[0];
  const int* ei = (const int*)d_in[1];
  const int* batch = (const int*)d_in[2];
  const float* W1 = (const float*)d_in[3];
  const float* b1 = (const float*)d_in[4];
  const float* gamma = (const float*)d_in[5];
  const float* beta = (const float*)d_in[6];
  const float* W2 = (const float*)d_in[7];
  const float* b2 = (const float*)d_in[8];
  int N = in_sizes[0] / D;
  int E = in_sizes[1] / 2;
  int Npad = (N + 63) & ~63;
  int gb = Npad / 64;
  int B = (E + EPB - 1) / EPB;
  int nbin = (N + 255) / 256;
  int M = nbin * B;

  float* out = (float*)d_out;
  float* node_pool = out;
  float* g_pool = out + (size_t)N * D;

  char* wp = (char*)d_ws;
  unsigned short* hx = (unsigned short*)wp;   wp += (size_t)Npad * D * 2;
  unsigned short* t = (unsigned short*)wp;    wp += (size_t)Npad * D * 2;
  unsigned short* hbuf[3];
  for (int l = 0; l < 3; ++l) { hbuf[l] = (unsigned short*)wp; wp += (size_t)Npad * D * 2; }
  unsigned short* wt = (unsigned short*)wp;   wp += (size_t)8 * D * D * 2;
  float* partials = (float*)wp;               wp += (size_t)gb * 256 * 4;
  float* partial2 = (float*)wp;               wp += (size_t)64 * 256 * 4;
  int* bound = (int*)wp;                      wp += (size_t)(GNUM + 4) * 4;
  int* rowptr = (int*)wp;                     wp += (size_t)(N + 1) * 4;
  int* perm = (int*)wp;                       wp += (size_t)Npad * 4;
  int* hist = (int*)wp;                       wp += (size_t)SH_MAX * 4;
  int* off = (int*)wp;                        wp += (size_t)SH_MAX * 4;
  int* col = (int*)wp;                        wp += (size_t)E * 4;
  int* sorted = (int*)wp;                     wp += (size_t)E * 4;

  int xblocks = (N * 32 + 255) / 256;
  k_prep<<<8 + xblocks, 256, 0, stream>>>(W1, W2, wt, x, hx, N * 32);
  k_hist<<<B, 256, 0, stream>>>(ei, E, B, nbin, hist);
  k_hscan<<<1, 1024, 0, stream>>>(hist, M, off, rowptr, N, E);
  k_scatter<<<B, 256, 0, stream>>>(ei, E, B, nbin, off, sorted);
  k_build<<<nbin, 256, 0, stream>>>(sorted, off, B, nbin, E, N, rowptr, col);
  k_perm<<<gb, 64, 0, stream>>>(rowptr, N, perm, batch, bound);

  for (int ll = 0; ll < LNUM; ++ll) {
    const unsigned short* hin = (ll == 0) ? hx : hbuf[ll - 1];
    k_layer1<<<gb, 256, 0, stream>>>(hin, rowptr, col, perm, wt + (size_t)ll * D * D,
                                     b1 + (size_t)ll * D, t, partials, N);
    k_red1<<<64, 256, 0, stream>>>(partials, gb, partial2);
    if (ll < LNUM - 1) {
      k_gemm2<<<gb, 256, 0, stream>>>(t, wt + (size_t)(LNUM + ll) * D * D,
                                      b2 + (size_t)ll * D, partial2,
                                      gamma + (size_t)ll * D, beta + (size_t)ll * D,
                                      hbuf[ll], N);
    } else {
      k_gemm2_last<<<gb, 256, 0, stream>>>(t, wt + (size_t)(LNUM + ll) * D * D,
                                           b2 + (size_t)ll * D, partial2,
                                           gamma + (size_t)ll * D, beta + (size_t)ll * D,
                                           hbuf[0], hbuf[1], hbuf[2], node_pool, N);
    }
  }
  k_gpool<<<GNUM, 256, 0, stream>>>(node_pool, bound, g_pool);
}